// Round 8
// baseline (206.572 us; speedup 1.0000x reference)
//
#include <hip/hip_runtime.h>
#include <hip/hip_bf16.h>
#include <math.h>

#define B_   4
#define C_   256
#define H_   56
#define W_   56
#define HW_  3136
#define OC1  128
#define NT   49
#define NP   64          // padded logit count
#define HP_  68          // 56 + 2*6 padded
#define M_TOT 12544      // B_*HW_
#define NSL  14          // K-split slices: 7 tap-rows x 2 cc-halves

typedef __attribute__((ext_vector_type(8))) short bf16x8;
typedef __attribute__((ext_vector_type(4))) float f32x4;

// ===========================================================================
// FAST PATH: fused-weight bf16 MFMA implicit GEMM (conv2 folded into conv1)
// logits = conv(x, Wf) + cb,  Wf[l,c,tap] = sum_oc W2[l,oc]*W1[oc,c,tap]
// xp2 layout: [cc 8][b 4][hp 68][wp 68][ci 32] bf16   (validated R4-R7)
// wfb layout: [tap 49][cc 8][ntile 4][lane 64][j 8] bf16 fragment order
// ===========================================================================

// Pack x (f32 NCHW) -> xp2, zero borders. One block per (cc, b, hp). (validated)
__global__ __launch_bounds__(256) void xpack2_kernel(const float* __restrict__ x,
                                                     __hip_bfloat16* __restrict__ xp)
{
    __shared__ short tile[HP_ * 32];     // [wp][ci]
    int bid = blockIdx.x;                // < 8*4*68 = 2176
    int cc = bid / (B_ * HP_);
    int r  = bid - cc * (B_ * HP_);
    int b  = r / HP_;
    int hp = r - b * HP_;
    int h  = hp - 6;
    int tid = threadIdx.x;

    if (h < 0 || h >= H_) {
        for (int idx = tid; idx < HP_ * 32; idx += 256) tile[idx] = 0;
    } else {
        int ci = tid >> 3;               // 0..31
        int wg = tid & 7;                // 0..7
        const float* xr = x + ((size_t)(b * C_ + cc * 32 + ci) * H_ + h) * W_;
        #pragma unroll
        for (int k = 0; k < 7; ++k) {
            int w = wg + 8 * k;          // covers 0..55 exactly
            __hip_bfloat16 v = __float2bfloat16(xr[w]);
            tile[(w + 6) * 32 + ci] = *(short*)&v;
        }
        for (int idx = tid; idx < 384; idx += 256) {
            int wp = idx >> 5;           // 0..11
            int wz = (wp < 6) ? wp : (wp + 56);
            tile[wz * 32 + (idx & 31)] = 0;
        }
    }
    __syncthreads();
    short* outp = (short*)xp + ((size_t)((cc * B_ + b) * HP_ + hp) * HP_) * 32;
    for (int idx = tid; idx < 272; idx += 256)
        *(bf16x8*)(outp + idx * 8) = *(bf16x8*)(tile + idx * 8);
}

// Fused-weight pack (validated R7) + cbias folded into block (0,0).
// Wf fragment order [tap][cc][ntile4][lane][j8]:
// n = ntile*16 + (l&15); c = cc*32 + (l>>4)*8 + j
__global__ __launch_bounds__(256) void wfuse_kernel(const float* __restrict__ W1,
                                                    const float* __restrict__ W2,
                                                    const float* __restrict__ b1,
                                                    const float* __restrict__ b2,
                                                    __hip_bfloat16* __restrict__ wfb,
                                                    float* __restrict__ cb)
{
    __shared__ float sW2[NP * 129];      // [n][oc], stride 129 kills bank conflicts
    __shared__ float sW1[128 * 32];      // [oc][ci]
    int tap = blockIdx.x;                // 0..48
    int cc  = blockIdx.y;                // 0..7
    int tid = threadIdx.x;

    for (int idx = tid; idx < NP * 128; idx += 256) {
        int n = idx >> 7, oc = idx & 127;
        sW2[n * 129 + oc] = (n < NT) ? W2[n * 128 + oc] : 0.0f;
    }
    for (int idx = tid; idx < 128 * 32; idx += 256) {
        int oc = idx >> 5, ci = idx & 31;
        sW1[idx] = W1[((size_t)(oc * C_ + cc * 32 + ci)) * NT + tap];
    }
    __syncthreads();

    int ntile = tid >> 6;
    int l     = tid & 63;
    int n     = ntile * 16 + (l & 15);
    int q     = l >> 4;

    float acc[8] = {0,0,0,0,0,0,0,0};
    for (int oc = 0; oc < 128; ++oc) {
        float w2 = sW2[n * 129 + oc];
        const float* r = &sW1[oc * 32 + q * 8];
        #pragma unroll
        for (int j = 0; j < 8; ++j)
            acc[j] += w2 * r[j];
    }

    short pk[8];
    #pragma unroll
    for (int j = 0; j < 8; ++j) {
        __hip_bfloat16 v = __float2bfloat16(acc[j]);
        pk[j] = *(short*)&v;
    }
    short* dst = (short*)wfb + ((size_t)(tap * 8 + cc) * 4 + ntile) * 512 + l * 8;
    *(bf16x8*)dst = *(bf16x8*)pk;

    // fold cbias here (removes a separate launch): cb[l] = b2[l] + W2[l,:]@b1
    if (tap == 0 && cc == 0 && tid < 64) {
        float a = 0.0f;
        if (tid < NT) {
            a = b2[tid];
            for (int oc = 0; oc < 128; ++oc)
                a += sW2[tid * 129 + oc] * b1[oc];
        }
        cb[tid] = a;
    }
}

// Fused conv implicit GEMM, K-split x2 (R8): each block = one (tap-row i,
// cc-half) pair, 28 K-steps. Grid 1456 -> ~5.7 blocks/CU (~23 waves/CU),
// doubling occupancy vs R7's 24%. Inner loop/indexing identical to the
// validated R7 kernel; only the cc range and kpart slice index changed.
__global__ __launch_bounds__(256) void conv1_mfma4(const __hip_bfloat16* __restrict__ xp,
                                                   const __hip_bfloat16* __restrict__ wfb,
                                                   float* __restrict__ kpart)
{
    const int bid = blockIdx.x;
    const int g   = bid & 7;              // presumed XCD (round-robin dispatch)
    const int kk  = bid >> 3;             // 0..181
    const int s   = (g * 98) >> 3;
    const int cnt = (((g + 1) * 98) >> 3) - s;   // 12 or 13
    const int slice = kk / cnt;           // 0..13
    if (slice >= NSL) return;
    const int mblk = s + (kk - slice * cnt);
    const int m0   = mblk * 128;
    const int i    = slice >> 1;          // tap row 0..6
    const int ch   = slice & 1;           // cc half: cc in [ch*4, ch*4+4)

    const int tid  = threadIdx.x;
    const int lane = tid & 63;
    const int wid  = tid >> 6;
    const int waveM = wid >> 1, waveN = wid & 1;
    const int quad = lane >> 4, l16 = lane & 15;

    const short* xps = (const short*)xp;
    const short* wbs = (const short*)wfb;
    const long CC_STRIDE = (long)B_ * HP_ * HP_ * 32;   // 591,872 elements

    long abase[4];
    #pragma unroll
    for (int mt = 0; mt < 4; ++mt) {
        int m = m0 + waveM * 64 + mt * 16 + l16;
        int b = m / HW_; int hw = m - b * HW_;
        int h = hw / W_; int w = hw - h * W_;
        abase[mt] = ((long)(b * HP_ + (h + 2 * i)) * HP_ + w) * 32 + quad * 8;
    }

    f32x4 acc[4][2];
    #pragma unroll
    for (int a = 0; a < 4; ++a)
        #pragma unroll
        for (int b2 = 0; b2 < 2; ++b2) acc[a][b2] = (f32x4){0.f, 0.f, 0.f, 0.f};

    const long bwave = (long)waveN * 1024 + lane * 8;   // waveN picks ntile pair

    #pragma unroll
    for (int cc4 = 0; cc4 < 4; ++cc4) {
        const int cc = ch * 4 + cc4;
        const long aoffc = (long)cc * CC_STRIDE;
        const long boffc = (long)cc * 2048;
        for (int j = 0; j < 7; ++j) {
            const long aoffj = aoffc + (long)j * 64;              // wp += 2
            const long boffj = (long)(i * 7 + j) * 16384 + boffc; // tap*8cc*4nt*512
            bf16x8 af[4], bfr[2];
            #pragma unroll
            for (int mt = 0; mt < 4; ++mt)
                af[mt] = *(const bf16x8*)(xps + abase[mt] + aoffj);
            #pragma unroll
            for (int nt = 0; nt < 2; ++nt)
                bfr[nt] = *(const bf16x8*)(wbs + boffj + (long)nt * 512 + bwave);
            #pragma unroll
            for (int mt = 0; mt < 4; ++mt)
                #pragma unroll
                for (int nt = 0; nt < 2; ++nt)
                    acc[mt][nt] = __builtin_amdgcn_mfma_f32_16x16x32_bf16(
                        af[mt], bfr[nt], acc[mt][nt], 0, 0, 0);
        }
    }

    // Store: C/D layout col(n)=lane&15, row(m)=quad*4+reg (validated)
    #pragma unroll
    for (int mt = 0; mt < 4; ++mt) {
        int mrow = m0 + waveM * 64 + mt * 16 + quad * 4;
        #pragma unroll
        for (int nt = 0; nt < 2; ++nt) {
            int n = waveN * 32 + nt * 16 + l16;
            float* dst = kpart + ((long)slice * M_TOT + mrow) * NP + n;
            #pragma unroll
            for (int r = 0; r < 4; ++r)
                dst[(long)r * NP] = acc[mt][nt][r];
        }
    }
}

// Fold 14 partial-logit slices + cb, softmax over 49, write pixel-major attnP.
// One wave per pixel; lane = logit. Fully coalesced reads/writes. (R7 + NSL=14)
__global__ __launch_bounds__(256) void attn_fold(const float* __restrict__ kpart,
                                                 const float* __restrict__ cb,
                                                 float* __restrict__ attnP)
{
    int tid  = threadIdx.x;
    int wid  = tid >> 6;
    int lane = tid & 63;
    int pix  = blockIdx.x * 4 + wid;     // < 12544

    const float* kp = kpart + (size_t)pix * NP + lane;
    float v = 0.0f;
    #pragma unroll
    for (int sp = 0; sp < NSL; ++sp)
        v += kp[(size_t)sp * M_TOT * NP];

    float logit = (lane < NT) ? (v + cb[lane]) : -INFINITY;
    float mx = logit;
    for (int s = 32; s > 0; s >>= 1) mx = fmaxf(mx, __shfl_xor(mx, s, 64));
    float e = (lane < NT) ? __expf(logit - mx) : 0.0f;
    float sum = e;
    for (int s = 32; s > 0; s >>= 1) sum += __shfl_xor(sum, s, 64);
    if (lane < NT)
        attnP[(size_t)pix * NT + lane] = e / sum;
}

// Weighted 49-tap gather (validated R7). Block = (bh, 16-channel group),
// XCD-swizzled. sX zero-padded -> mask-free inner loop.
__global__ __launch_bounds__(256) void out_kernel4(const float* __restrict__ x,
                                                   const float* __restrict__ attnP,
                                                   float* __restrict__ out)
{
    __shared__ float sX[7 * HP_ * 16];   // [i][wp][c] 30.5 KB
    __shared__ float sA[56 * NT];        // [w][l] 10.7 KB

    int bid = blockIdx.x;                // < 3584
    int g   = bid & 7;                   // presumed XCD
    int s   = bid >> 3;                  // 0..447
    int bh  = g * 28 + (s % 28);         // 28 bh-rows per XCD slot
    int cg  = s / 28;                    // 0..15
    int b   = bh / H_;
    int h   = bh - b * H_;
    int c0  = cg * 16;
    int tid = threadIdx.x;

    for (int idx = tid; idx < 7 * HP_ * 16; idx += 256)
        sX[idx] = 0.0f;
    __syncthreads();

    {
        const float* ap = attnP + ((size_t)(b * HW_) + h * W_) * NT;
        for (int idx = tid; idx < W_ * NT; idx += 256)
            sA[idx] = ap[idx];
    }
    {
        int c  = tid >> 4;
        int wg = tid & 15;
        const float* xc = x + (size_t)(b * C_ + c0 + c) * HW_;
        #pragma unroll
        for (int i = 0; i < 7; ++i) {
            int ih = h + 2 * i - 6;
            if (ih < 0 || ih >= H_) continue;
            const float* xr = xc + ih * W_;
            #pragma unroll
            for (int k = 0; k < 4; ++k) {
                int w = wg + 16 * k;
                if (w < W_)
                    sX[(i * HP_ + (w + 6)) * 16 + c] = xr[w];
            }
        }
    }
    __syncthreads();

    int lane = tid & 63;
    int wid  = tid >> 6;                 // wave -> channels c0+wid*4 .. +3
    int w    = lane;
    bool active = (w < W_);
    int wc = active ? w : (W_ - 1);

    float aR[NT];
    #pragma unroll
    for (int l = 0; l < NT; ++l)
        aR[l] = sA[wc * NT + l];

    f32x4 acc = (f32x4){0.f, 0.f, 0.f, 0.f};
    #pragma unroll
    for (int i = 0; i < 7; ++i) {
        #pragma unroll
        for (int j = 0; j < 7; ++j) {
            f32x4 xv = *(const f32x4*)&sX[(i * HP_ + (wc + 2 * j)) * 16 + wid * 4];
            float a = aR[i * 7 + j];
            acc.x += a * xv.x; acc.y += a * xv.y;
            acc.z += a * xv.z; acc.w += a * xv.w;
        }
    }

    if (active) {
        size_t o = ((size_t)(b * C_ + c0 + wid * 4)) * HW_ + h * W_ + w;
        out[o + 0 * HW_] = acc.x;
        out[o + 1 * HW_] = acc.y;
        out[o + 2 * HW_] = acc.z;
        out[o + 3 * HW_] = acc.w;
    }
}

// ===========================================================================
// FALLBACK PATH (R1, proven): used only if ws_size < fast-path need
// ===========================================================================
__global__ __launch_bounds__(256) void wt_kernel(const float* __restrict__ W1,
                                                 float* __restrict__ wT)
{
    int idx = blockIdx.x * 256 + threadIdx.x;
    int oc = idx & 127;
    int ct = idx >> 7;
    wT[idx] = W1[oc * (C_ * NT) + ct];
}

__global__ __launch_bounds__(256) void conv1_kernel(const float* __restrict__ x,
                                                    const float* __restrict__ wT,
                                                    const float* __restrict__ b1,
                                                    float* __restrict__ k)
{
    int tid = threadIdx.x;
    int w   = tid & 63;
    int ty  = tid >> 6;
    int h   = blockIdx.x * 4 + ty;
    int oc0 = blockIdx.y * 8;
    int b   = blockIdx.z;

    const float* xb = x + (size_t)b * C_ * HW_;
    float acc[8] = {0.f,0.f,0.f,0.f,0.f,0.f,0.f,0.f};

    for (int i = 0; i < 7; ++i) {
        int ih = h + 2 * i - 6;
        if (ih < 0 || ih >= H_) continue;
        for (int j = 0; j < 7; ++j) {
            int iw = w + 2 * j - 6;
            bool v  = (iw >= 0) && (iw < W_);
            float m = v ? 1.0f : 0.0f;
            const float* xr = xb + ih * W_ + (v ? iw : 0);
            const float* wr = wT + (size_t)(i * 7 + j) * OC1 + oc0;
            #pragma unroll 4
            for (int c = 0; c < C_; ++c) {
                float xv = m * xr[(size_t)c * HW_];
                const float4 w0 = *(const float4*)(wr + (size_t)c * NT * OC1);
                const float4 w1 = *(const float4*)(wr + (size_t)c * NT * OC1 + 4);
                acc[0] += xv * w0.x; acc[1] += xv * w0.y;
                acc[2] += xv * w0.z; acc[3] += xv * w0.w;
                acc[4] += xv * w1.x; acc[5] += xv * w1.y;
                acc[6] += xv * w1.z; acc[7] += xv * w1.w;
            }
        }
    }
    if (w < W_) {
        size_t o = ((size_t)(b * OC1 + oc0)) * HW_ + h * W_ + w;
        #pragma unroll
        for (int q = 0; q < 8; ++q)
            k[o + (size_t)q * HW_] = acc[q] + b1[oc0 + q];
    }
}

__global__ __launch_bounds__(256) void attn_kernel(const float* __restrict__ kin,
                                                   const float* __restrict__ W2,
                                                   const float* __restrict__ b2,
                                                   float* __restrict__ attn)
{
    __shared__ float sW2[128 * 49];
    int tid = threadIdx.x;
    for (int idx = tid; idx < 128 * 49; idx += 256) {
        int c = idx / 49, l = idx - c * 49;
        sW2[idx] = W2[l * 128 + c];
    }
    __syncthreads();

    int wid  = tid >> 6;
    int lane = tid & 63;
    int pix  = blockIdx.x * 4 + wid;
    int b    = pix / HW_;
    int hw   = pix - b * HW_;
    int l    = (lane < 49) ? lane : 0;

    const float* kb = kin + (size_t)b * OC1 * HW_ + hw;
    float acc = b2[l];
    #pragma unroll 8
    for (int c = 0; c < 128; ++c)
        acc += kb[(size_t)c * HW_] * sW2[c * 49 + l];

    float logit = (lane < 49) ? acc : -INFINITY;
    float mx = logit;
    for (int s = 32; s > 0; s >>= 1) mx = fmaxf(mx, __shfl_xor(mx, s, 64));
    float e = (lane < 49) ? __expf(logit - mx) : 0.0f;
    float sum = e;
    for (int s = 32; s > 0; s >>= 1) sum += __shfl_xor(sum, s, 64);
    if (lane < 49)
        attn[((size_t)b * NT + lane) * HW_ + hw] = e / sum;
}

__global__ __launch_bounds__(256) void out_kernel(const float* __restrict__ x,
                                                  const float* __restrict__ attn,
                                                  float* __restrict__ out)
{
    int idx = blockIdx.x * 256 + threadIdx.x;
    int w  = idx % 56;
    int t  = idx / 56;
    int h  = t % 56;
    int t2 = t / 56;
    int c  = t2 & 255;
    int b  = t2 >> 8;

    const float* xb = x + (size_t)(b * C_ + c) * HW_;
    const float* ab = attn + (size_t)b * NT * HW_ + h * W_ + w;

    float acc = 0.f;
    #pragma unroll
    for (int i = 0; i < 7; ++i) {
        int ih = h + 2 * i - 6;
        bool hv = (ih >= 0) && (ih < H_);
        #pragma unroll
        for (int j = 0; j < 7; ++j) {
            int iw = w + 2 * j - 6;
            bool v  = hv && (iw >= 0) && (iw < W_);
            float m = v ? 1.0f : 0.0f;
            int off = v ? (ih * W_ + iw) : 0;
            acc += (m * xb[off]) * ab[(size_t)(i * 7 + j) * HW_];
        }
    }
    out[idx] = acc;
}

// ===========================================================================
extern "C" void kernel_launch(void* const* d_in, const int* in_sizes, int n_in,
                              void* d_out, int out_size, void* d_ws, size_t ws_size,
                              hipStream_t stream)
{
    const float* x  = (const float*)d_in[0];
    const float* W1 = (const float*)d_in[1];
    const float* b1 = (const float*)d_in[2];
    const float* W2 = (const float*)d_in[3];
    const float* b2 = (const float*)d_in[4];
    float* out = (float*)d_out;

    // fast-path ws layout (bytes)
    const size_t xp_b    = (size_t)B_ * HP_ * HP_ * 256 * 2;        //  9,469,952
    const size_t wfb_b   = (size_t)NT * 8 * 4 * 64 * 8 * 2;         //  1,605,632
    const size_t kpart_b = (size_t)NSL * M_TOT * NP * 4;            // 44,957,696
    const size_t attn_b  = (size_t)M_TOT * NT * 4;                  //  2,458,624
    const size_t cb_b    = 256;
    const size_t need = xp_b + wfb_b + kpart_b + attn_b + cb_b;     // ~58.5 MB

    if (ws_size >= need) {
        char* base = (char*)d_ws;
        __hip_bfloat16* xp  = (__hip_bfloat16*)base;
        __hip_bfloat16* wfb = (__hip_bfloat16*)(base + xp_b);
        float* kpart = (float*)(base + xp_b + wfb_b);
        float* attnP = (float*)(base + xp_b + wfb_b + kpart_b);
        float* cb    = (float*)(base + xp_b + wfb_b + kpart_b + attn_b);

        xpack2_kernel<<<2176, 256, 0, stream>>>(x, xp);
        wfuse_kernel <<<dim3(49, 8), 256, 0, stream>>>(W1, W2, b1, b2, wfb, cb);
        conv1_mfma4  <<<1456, 256, 0, stream>>>(xp, wfb, kpart);
        attn_fold    <<<3136, 256, 0, stream>>>(kpart, cb, attnP);
        out_kernel4  <<<3584, 256, 0, stream>>>(x, attnP, out);
    } else {
        // R1 fallback (~14.6 MB)
        float* wT   = (float*)d_ws;
        float* kbuf = wT + 1605632;
        float* attn = kbuf + 1605632;
        wt_kernel   <<<6272, 256, 0, stream>>>(W1, wT);
        conv1_kernel<<<dim3(14, 16, 4), 256, 0, stream>>>(x, wT, b1, kbuf);
        attn_kernel <<<3136, 256, 0, stream>>>(kbuf, W2, b2, attn);
        out_kernel  <<<12544, 256, 0, stream>>>(x, attn, out);
    }
}

// Round 9
// 193.511 us; speedup vs baseline: 1.0675x; 1.0675x over previous
//
#include <hip/hip_runtime.h>
#include <hip/hip_bf16.h>
#include <math.h>

#define B_   4
#define C_   256
#define H_   56
#define W_   56
#define HW_  3136
#define OC1  128
#define NT   49
#define NP   64          // padded logit count
#define HP_  68          // 56 + 2*6 padded
#define M_TOT 12544      // B_*HW_
#define NSL  14          // K-split slices: 7 tap-rows x 2 cc-halves

typedef __attribute__((ext_vector_type(8))) short bf16x8;
typedef __attribute__((ext_vector_type(4))) float f32x4;

// ===========================================================================
// FAST PATH: fused-weight bf16 MFMA implicit GEMM (conv2 folded into conv1)
// logits = conv(x, Wf) + cb,  Wf[l,c,tap] = sum_oc W2[l,oc]*W1[oc,c,tap]
// xp2 layout: [cc 8][b 4][hp 68][wp 68][ci 32] bf16   (validated R4-R8)
// wfb layout: [tap 49][cc 8][ntile 4][lane 64][j 8] bf16 fragment order
// ===========================================================================

// Pack x (f32 NCHW) -> xp2, zero borders. One block per (cc, b, hp). (validated)
__global__ __launch_bounds__(256) void xpack2_kernel(const float* __restrict__ x,
                                                     __hip_bfloat16* __restrict__ xp)
{
    __shared__ short tile[HP_ * 32];     // [wp][ci]
    int bid = blockIdx.x;                // < 8*4*68 = 2176
    int cc = bid / (B_ * HP_);
    int r  = bid - cc * (B_ * HP_);
    int b  = r / HP_;
    int hp = r - b * HP_;
    int h  = hp - 6;
    int tid = threadIdx.x;

    if (h < 0 || h >= H_) {
        for (int idx = tid; idx < HP_ * 32; idx += 256) tile[idx] = 0;
    } else {
        int ci = tid >> 3;               // 0..31
        int wg = tid & 7;                // 0..7
        const float* xr = x + ((size_t)(b * C_ + cc * 32 + ci) * H_ + h) * W_;
        #pragma unroll
        for (int k = 0; k < 7; ++k) {
            int w = wg + 8 * k;          // covers 0..55 exactly
            __hip_bfloat16 v = __float2bfloat16(xr[w]);
            tile[(w + 6) * 32 + ci] = *(short*)&v;
        }
        for (int idx = tid; idx < 384; idx += 256) {
            int wp = idx >> 5;           // 0..11
            int wz = (wp < 6) ? wp : (wp + 56);
            tile[wz * 32 + (idx & 31)] = 0;
        }
    }
    __syncthreads();
    short* outp = (short*)xp + ((size_t)((cc * B_ + b) * HP_ + hp) * HP_) * 32;
    for (int idx = tid; idx < 272; idx += 256)
        *(bf16x8*)(outp + idx * 8) = *(bf16x8*)(tile + idx * 8);
}

// Fused-weight pack (validated R7/R8) + cbias folded into block (0,0).
// Wf fragment order [tap][cc][ntile4][lane][j8]:
// n = ntile*16 + (l&15); c = cc*32 + (l>>4)*8 + j
__global__ __launch_bounds__(256) void wfuse_kernel(const float* __restrict__ W1,
                                                    const float* __restrict__ W2,
                                                    const float* __restrict__ b1,
                                                    const float* __restrict__ b2,
                                                    __hip_bfloat16* __restrict__ wfb,
                                                    float* __restrict__ cb)
{
    __shared__ float sW2[NP * 129];      // [n][oc], stride 129 kills bank conflicts
    __shared__ float sW1[128 * 32];      // [oc][ci]
    int tap = blockIdx.x;                // 0..48
    int cc  = blockIdx.y;                // 0..7
    int tid = threadIdx.x;

    for (int idx = tid; idx < NP * 128; idx += 256) {
        int n = idx >> 7, oc = idx & 127;
        sW2[n * 129 + oc] = (n < NT) ? W2[n * 128 + oc] : 0.0f;
    }
    for (int idx = tid; idx < 128 * 32; idx += 256) {
        int oc = idx >> 5, ci = idx & 31;
        sW1[idx] = W1[((size_t)(oc * C_ + cc * 32 + ci)) * NT + tap];
    }
    __syncthreads();

    int ntile = tid >> 6;
    int l     = tid & 63;
    int n     = ntile * 16 + (l & 15);
    int q     = l >> 4;

    float acc[8] = {0,0,0,0,0,0,0,0};
    for (int oc = 0; oc < 128; ++oc) {
        float w2 = sW2[n * 129 + oc];
        const float* r = &sW1[oc * 32 + q * 8];
        #pragma unroll
        for (int j = 0; j < 8; ++j)
            acc[j] += w2 * r[j];
    }

    short pk[8];
    #pragma unroll
    for (int j = 0; j < 8; ++j) {
        __hip_bfloat16 v = __float2bfloat16(acc[j]);
        pk[j] = *(short*)&v;
    }
    short* dst = (short*)wfb + ((size_t)(tap * 8 + cc) * 4 + ntile) * 512 + l * 8;
    *(bf16x8*)dst = *(bf16x8*)pk;

    // fold cbias here (removes a separate launch): cb[l] = b2[l] + W2[l,:]@b1
    if (tap == 0 && cc == 0 && tid < 64) {
        float a = 0.0f;
        if (tid < NT) {
            a = b2[tid];
            for (int oc = 0; oc < 128; ++oc)
                a += sW2[tid * 129 + oc] * b1[oc];
        }
        cb[tid] = a;
    }
}

// Fused conv implicit GEMM (R9): wave tile M64xN64, 4 waves stacked in M ->
// block tile M256xN64. Grid = 8 XCD slots x 98 = 784 (49 m-blocks x 14
// slices, XCD-swizzled). A loaded from global exactly once per block (no
// cross-wave dup); B(i,cc) staged in LDS (28 KB) once per cc-phase and read
// via conflict-free ds_read_b128. Summation order (cc outer, j inner) is
// bit-identical to the validated R8 kernel.
__global__ __launch_bounds__(256) void conv1_mfma5(const __hip_bfloat16* __restrict__ xp,
                                                   const __hip_bfloat16* __restrict__ wfb,
                                                   float* __restrict__ kpart)
{
    __shared__ short sB[28 * 512];        // [j7][nt4][lane64][8] = 28 KB

    const int bid = blockIdx.x;
    const int g   = bid & 7;              // presumed XCD (round-robin dispatch)
    const int kk  = bid >> 3;             // 0..97
    const int s   = (g * 49) >> 3;
    const int cnt = (((g + 1) * 49) >> 3) - s;   // 6 or 7
    const int slice = kk / cnt;           // 0..13 valid
    if (slice >= NSL) return;
    const int mblk = s + (kk - slice * cnt);
    const int m0   = mblk * 256;
    const int i    = slice >> 1;          // tap row 0..6
    const int ch   = slice & 1;           // cc half: cc in [ch*4, ch*4+4)

    const int tid  = threadIdx.x;
    const int lane = tid & 63;
    const int wid  = tid >> 6;            // waveM: wave owns rows m0+wid*64..+63
    const int quad = lane >> 4, l16 = lane & 15;

    const short* xps = (const short*)xp;
    const short* wbs = (const short*)wfb;
    const long CC_STRIDE = (long)B_ * HP_ * HP_ * 32;   // 591,872 elements

    long abase[4];
    #pragma unroll
    for (int mt = 0; mt < 4; ++mt) {
        int m = m0 + wid * 64 + mt * 16 + l16;
        int b = m / HW_; int hw = m - b * HW_;
        int h = hw / W_; int w = hw - h * W_;
        abase[mt] = ((long)(b * HP_ + (h + 2 * i)) * HP_ + w) * 32 + quad * 8;
    }

    f32x4 acc[4][4];
    #pragma unroll
    for (int a = 0; a < 4; ++a)
        #pragma unroll
        for (int b2 = 0; b2 < 4; ++b2) acc[a][b2] = (f32x4){0.f, 0.f, 0.f, 0.f};

    for (int cc4 = 0; cc4 < 4; ++cc4) {
        const int cc = ch * 4 + cc4;
        __syncthreads();                  // guard prev phase's reads vs restage
        // stage B(i,cc): 28 chunks of 512 shorts; wave w does q = w + 4k
        #pragma unroll
        for (int k = 0; k < 7; ++k) {
            int q = wid + 4 * k;          // 0..27
            int j = q >> 2, nt = q & 3;
            const short* src = wbs + ((((long)(i * 7 + j) * 8 + cc) * 4 + nt) << 9) + lane * 8;
            bf16x8 v = *(const bf16x8*)src;
            *(bf16x8*)(&sB[q * 512 + lane * 8]) = v;
        }
        __syncthreads();

        const long aoffc = (long)cc * CC_STRIDE;
        for (int j = 0; j < 7; ++j) {
            const long aoffj = aoffc + (long)j * 64;   // wp += 2 per j
            bf16x8 af[4], bfr[4];
            #pragma unroll
            for (int mt = 0; mt < 4; ++mt)
                af[mt] = *(const bf16x8*)(xps + abase[mt] + aoffj);
            #pragma unroll
            for (int nt = 0; nt < 4; ++nt)
                bfr[nt] = *(const bf16x8*)(&sB[(j * 4 + nt) * 512 + lane * 8]);
            #pragma unroll
            for (int mt = 0; mt < 4; ++mt)
                #pragma unroll
                for (int nt = 0; nt < 4; ++nt)
                    acc[mt][nt] = __builtin_amdgcn_mfma_f32_16x16x32_bf16(
                        af[mt], bfr[nt], acc[mt][nt], 0, 0, 0);
        }
    }

    // Store: C/D layout col(n)=lane&15, row(m)=quad*4+reg (validated)
    #pragma unroll
    for (int mt = 0; mt < 4; ++mt) {
        int mrow = m0 + wid * 64 + mt * 16 + quad * 4;
        #pragma unroll
        for (int nt = 0; nt < 4; ++nt) {
            int n = nt * 16 + l16;
            float* dst = kpart + ((long)slice * M_TOT + mrow) * NP + n;
            #pragma unroll
            for (int r = 0; r < 4; ++r)
                dst[(long)r * NP] = acc[mt][nt][r];
        }
    }
}

// Fold 14 partial-logit slices + cb, softmax over 49, write pixel-major attnP.
// One wave per pixel; lane = logit. Fully coalesced reads/writes. (validated R8)
__global__ __launch_bounds__(256) void attn_fold(const float* __restrict__ kpart,
                                                 const float* __restrict__ cb,
                                                 float* __restrict__ attnP)
{
    int tid  = threadIdx.x;
    int wid  = tid >> 6;
    int lane = tid & 63;
    int pix  = blockIdx.x * 4 + wid;     // < 12544

    const float* kp = kpart + (size_t)pix * NP + lane;
    float v = 0.0f;
    #pragma unroll
    for (int sp = 0; sp < NSL; ++sp)
        v += kp[(size_t)sp * M_TOT * NP];

    float logit = (lane < NT) ? (v + cb[lane]) : -INFINITY;
    float mx = logit;
    for (int s = 32; s > 0; s >>= 1) mx = fmaxf(mx, __shfl_xor(mx, s, 64));
    float e = (lane < NT) ? __expf(logit - mx) : 0.0f;
    float sum = e;
    for (int s = 32; s > 0; s >>= 1) sum += __shfl_xor(sum, s, 64);
    if (lane < NT)
        attnP[(size_t)pix * NT + lane] = e / sum;
}

// Weighted 49-tap gather (validated R7/R8). Block = (bh, 16-channel group),
// XCD-swizzled. sX zero-padded -> mask-free inner loop.
__global__ __launch_bounds__(256) void out_kernel4(const float* __restrict__ x,
                                                   const float* __restrict__ attnP,
                                                   float* __restrict__ out)
{
    __shared__ float sX[7 * HP_ * 16];   // [i][wp][c] 30.5 KB
    __shared__ float sA[56 * NT];        // [w][l] 10.7 KB

    int bid = blockIdx.x;                // < 3584
    int g   = bid & 7;                   // presumed XCD
    int s   = bid >> 3;                  // 0..447
    int bh  = g * 28 + (s % 28);         // 28 bh-rows per XCD slot
    int cg  = s / 28;                    // 0..15
    int b   = bh / H_;
    int h   = bh - b * H_;
    int c0  = cg * 16;
    int tid = threadIdx.x;

    for (int idx = tid; idx < 7 * HP_ * 16; idx += 256)
        sX[idx] = 0.0f;
    __syncthreads();

    {
        const float* ap = attnP + ((size_t)(b * HW_) + h * W_) * NT;
        for (int idx = tid; idx < W_ * NT; idx += 256)
            sA[idx] = ap[idx];
    }
    {
        int c  = tid >> 4;
        int wg = tid & 15;
        const float* xc = x + (size_t)(b * C_ + c0 + c) * HW_;
        #pragma unroll
        for (int i = 0; i < 7; ++i) {
            int ih = h + 2 * i - 6;
            if (ih < 0 || ih >= H_) continue;
            const float* xr = xc + ih * W_;
            #pragma unroll
            for (int k = 0; k < 4; ++k) {
                int w = wg + 16 * k;
                if (w < W_)
                    sX[(i * HP_ + (w + 6)) * 16 + c] = xr[w];
            }
        }
    }
    __syncthreads();

    int lane = tid & 63;
    int wid  = tid >> 6;                 // wave -> channels c0+wid*4 .. +3
    int w    = lane;
    bool active = (w < W_);
    int wc = active ? w : (W_ - 1);

    float aR[NT];
    #pragma unroll
    for (int l = 0; l < NT; ++l)
        aR[l] = sA[wc * NT + l];

    f32x4 acc = (f32x4){0.f, 0.f, 0.f, 0.f};
    #pragma unroll
    for (int i = 0; i < 7; ++i) {
        #pragma unroll
        for (int j = 0; j < 7; ++j) {
            f32x4 xv = *(const f32x4*)&sX[(i * HP_ + (wc + 2 * j)) * 16 + wid * 4];
            float a = aR[i * 7 + j];
            acc.x += a * xv.x; acc.y += a * xv.y;
            acc.z += a * xv.z; acc.w += a * xv.w;
        }
    }

    if (active) {
        size_t o = ((size_t)(b * C_ + c0 + wid * 4)) * HW_ + h * W_ + w;
        out[o + 0 * HW_] = acc.x;
        out[o + 1 * HW_] = acc.y;
        out[o + 2 * HW_] = acc.z;
        out[o + 3 * HW_] = acc.w;
    }
}

// ===========================================================================
// FALLBACK PATH (R1, proven): used only if ws_size < fast-path need
// ===========================================================================
__global__ __launch_bounds__(256) void wt_kernel(const float* __restrict__ W1,
                                                 float* __restrict__ wT)
{
    int idx = blockIdx.x * 256 + threadIdx.x;
    int oc = idx & 127;
    int ct = idx >> 7;
    wT[idx] = W1[oc * (C_ * NT) + ct];
}

__global__ __launch_bounds__(256) void conv1_kernel(const float* __restrict__ x,
                                                    const float* __restrict__ wT,
                                                    const float* __restrict__ b1,
                                                    float* __restrict__ k)
{
    int tid = threadIdx.x;
    int w   = tid & 63;
    int ty  = tid >> 6;
    int h   = blockIdx.x * 4 + ty;
    int oc0 = blockIdx.y * 8;
    int b   = blockIdx.z;

    const float* xb = x + (size_t)b * C_ * HW_;
    float acc[8] = {0.f,0.f,0.f,0.f,0.f,0.f,0.f,0.f};

    for (int i = 0; i < 7; ++i) {
        int ih = h + 2 * i - 6;
        if (ih < 0 || ih >= H_) continue;
        for (int j = 0; j < 7; ++j) {
            int iw = w + 2 * j - 6;
            bool v  = (iw >= 0) && (iw < W_);
            float m = v ? 1.0f : 0.0f;
            const float* xr = xb + ih * W_ + (v ? iw : 0);
            const float* wr = wT + (size_t)(i * 7 + j) * OC1 + oc0;
            #pragma unroll 4
            for (int c = 0; c < C_; ++c) {
                float xv = m * xr[(size_t)c * HW_];
                const float4 w0 = *(const float4*)(wr + (size_t)c * NT * OC1);
                const float4 w1 = *(const float4*)(wr + (size_t)c * NT * OC1 + 4);
                acc[0] += xv * w0.x; acc[1] += xv * w0.y;
                acc[2] += xv * w0.z; acc[3] += xv * w0.w;
                acc[4] += xv * w1.x; acc[5] += xv * w1.y;
                acc[6] += xv * w1.z; acc[7] += xv * w1.w;
            }
        }
    }
    if (w < W_) {
        size_t o = ((size_t)(b * OC1 + oc0)) * HW_ + h * W_ + w;
        #pragma unroll
        for (int q = 0; q < 8; ++q)
            k[o + (size_t)q * HW_] = acc[q] + b1[oc0 + q];
    }
}

__global__ __launch_bounds__(256) void attn_kernel(const float* __restrict__ kin,
                                                   const float* __restrict__ W2,
                                                   const float* __restrict__ b2,
                                                   float* __restrict__ attn)
{
    __shared__ float sW2[128 * 49];
    int tid = threadIdx.x;
    for (int idx = tid; idx < 128 * 49; idx += 256) {
        int c = idx / 49, l = idx - c * 49;
        sW2[idx] = W2[l * 128 + c];
    }
    __syncthreads();

    int wid  = tid >> 6;
    int lane = tid & 63;
    int pix  = blockIdx.x * 4 + wid;
    int b    = pix / HW_;
    int hw   = pix - b * HW_;
    int l    = (lane < 49) ? lane : 0;

    const float* kb = kin + (size_t)b * OC1 * HW_ + hw;
    float acc = b2[l];
    #pragma unroll 8
    for (int c = 0; c < 128; ++c)
        acc += kb[(size_t)c * HW_] * sW2[c * 49 + l];

    float logit = (lane < 49) ? acc : -INFINITY;
    float mx = logit;
    for (int s = 32; s > 0; s >>= 1) mx = fmaxf(mx, __shfl_xor(mx, s, 64));
    float e = (lane < 49) ? __expf(logit - mx) : 0.0f;
    float sum = e;
    for (int s = 32; s > 0; s >>= 1) sum += __shfl_xor(sum, s, 64);
    if (lane < 49)
        attn[((size_t)b * NT + lane) * HW_ + hw] = e / sum;
}

__global__ __launch_bounds__(256) void out_kernel(const float* __restrict__ x,
                                                  const float* __restrict__ attn,
                                                  float* __restrict__ out)
{
    int idx = blockIdx.x * 256 + threadIdx.x;
    int w  = idx % 56;
    int t  = idx / 56;
    int h  = t % 56;
    int t2 = t / 56;
    int c  = t2 & 255;
    int b  = t2 >> 8;

    const float* xb = x + (size_t)(b * C_ + c) * HW_;
    const float* ab = attn + (size_t)b * NT * HW_ + h * W_ + w;

    float acc = 0.f;
    #pragma unroll
    for (int i = 0; i < 7; ++i) {
        int ih = h + 2 * i - 6;
        bool hv = (ih >= 0) && (ih < H_);
        #pragma unroll
        for (int j = 0; j < 7; ++j) {
            int iw = w + 2 * j - 6;
            bool v  = hv && (iw >= 0) && (iw < W_);
            float m = v ? 1.0f : 0.0f;
            int off = v ? (ih * W_ + iw) : 0;
            acc += (m * xb[off]) * ab[(size_t)(i * 7 + j) * HW_];
        }
    }
    out[idx] = acc;
}

// ===========================================================================
extern "C" void kernel_launch(void* const* d_in, const int* in_sizes, int n_in,
                              void* d_out, int out_size, void* d_ws, size_t ws_size,
                              hipStream_t stream)
{
    const float* x  = (const float*)d_in[0];
    const float* W1 = (const float*)d_in[1];
    const float* b1 = (const float*)d_in[2];
    const float* W2 = (const float*)d_in[3];
    const float* b2 = (const float*)d_in[4];
    float* out = (float*)d_out;

    // fast-path ws layout (bytes)
    const size_t xp_b    = (size_t)B_ * HP_ * HP_ * 256 * 2;        //  9,469,952
    const size_t wfb_b   = (size_t)NT * 8 * 4 * 64 * 8 * 2;         //  1,605,632
    const size_t kpart_b = (size_t)NSL * M_TOT * NP * 4;            // 44,957,696
    const size_t attn_b  = (size_t)M_TOT * NT * 4;                  //  2,458,624
    const size_t cb_b    = 256;
    const size_t need = xp_b + wfb_b + kpart_b + attn_b + cb_b;     // ~58.5 MB

    if (ws_size >= need) {
        char* base = (char*)d_ws;
        __hip_bfloat16* xp  = (__hip_bfloat16*)base;
        __hip_bfloat16* wfb = (__hip_bfloat16*)(base + xp_b);
        float* kpart = (float*)(base + xp_b + wfb_b);
        float* attnP = (float*)(base + xp_b + wfb_b + kpart_b);
        float* cb    = (float*)(base + xp_b + wfb_b + kpart_b + attn_b);

        xpack2_kernel<<<2176, 256, 0, stream>>>(x, xp);
        wfuse_kernel <<<dim3(49, 8), 256, 0, stream>>>(W1, W2, b1, b2, wfb, cb);
        conv1_mfma5  <<<784, 256, 0, stream>>>(xp, wfb, kpart);
        attn_fold    <<<3136, 256, 0, stream>>>(kpart, cb, attnP);
        out_kernel4  <<<3584, 256, 0, stream>>>(x, attnP, out);
    } else {
        // R1 fallback (~14.6 MB)
        float* wT   = (float*)d_ws;
        float* kbuf = wT + 1605632;
        float* attn = kbuf + 1605632;
        wt_kernel   <<<6272, 256, 0, stream>>>(W1, wT);
        conv1_kernel<<<dim3(14, 16, 4), 256, 0, stream>>>(x, wT, b1, kbuf);
        attn_kernel <<<3136, 256, 0, stream>>>(kbuf, W2, b2, attn);
        out_kernel  <<<12544, 256, 0, stream>>>(x, attn, out);
    }
}

// Round 10
// 183.424 us; speedup vs baseline: 1.1262x; 1.0550x over previous
//
#include <hip/hip_runtime.h>
#include <hip/hip_bf16.h>
#include <math.h>

#define B_   4
#define C_   256
#define H_   56
#define W_   56
#define HW_  3136
#define OC1  128
#define NT   49
#define NP   64          // padded logit count
#define HP_  68          // 56 + 2*6 padded
#define M_TOT 12544      // B_*HW_
#define NSL  14          // K-split slices: 7 tap-rows x 2 cc-halves

typedef __attribute__((ext_vector_type(8))) short bf16x8;
typedef __attribute__((ext_vector_type(4))) float f32x4;

// ===========================================================================
// FAST PATH: fused-weight bf16 MFMA implicit GEMM (conv2 folded into conv1)
// logits = conv(x, Wf) + cb,  Wf[l,c,tap] = sum_oc W2[l,oc]*W1[oc,c,tap]
// xp2 layout: [cc 8][b 4][hp 68][wp 68][ci 32] bf16   (validated R4-R9)
// wfb layout: [tap 49][cc 8][ntile 4][lane 64][j 8] bf16 fragment order
// ===========================================================================

// Pack x (f32 NCHW) -> xp2, zero borders. One block per (cc, b, hp). (validated)
__global__ __launch_bounds__(256) void xpack2_kernel(const float* __restrict__ x,
                                                     __hip_bfloat16* __restrict__ xp)
{
    __shared__ short tile[HP_ * 32];     // [wp][ci]
    int bid = blockIdx.x;                // < 8*4*68 = 2176
    int cc = bid / (B_ * HP_);
    int r  = bid - cc * (B_ * HP_);
    int b  = r / HP_;
    int hp = r - b * HP_;
    int h  = hp - 6;
    int tid = threadIdx.x;

    if (h < 0 || h >= H_) {
        for (int idx = tid; idx < HP_ * 32; idx += 256) tile[idx] = 0;
    } else {
        int ci = tid >> 3;               // 0..31
        int wg = tid & 7;                // 0..7
        const float* xr = x + ((size_t)(b * C_ + cc * 32 + ci) * H_ + h) * W_;
        #pragma unroll
        for (int k = 0; k < 7; ++k) {
            int w = wg + 8 * k;          // covers 0..55 exactly
            __hip_bfloat16 v = __float2bfloat16(xr[w]);
            tile[(w + 6) * 32 + ci] = *(short*)&v;
        }
        for (int idx = tid; idx < 384; idx += 256) {
            int wp = idx >> 5;           // 0..11
            int wz = (wp < 6) ? wp : (wp + 56);
            tile[wz * 32 + (idx & 31)] = 0;
        }
    }
    __syncthreads();
    short* outp = (short*)xp + ((size_t)((cc * B_ + b) * HP_ + hp) * HP_) * 32;
    for (int idx = tid; idx < 272; idx += 256)
        *(bf16x8*)(outp + idx * 8) = *(bf16x8*)(tile + idx * 8);
}

// Fused-weight pack (validated R7/R8) + cbias folded into block (0,0).
// Wf fragment order [tap][cc][ntile4][lane][j8]:
// n = ntile*16 + (l&15); c = cc*32 + (l>>4)*8 + j
__global__ __launch_bounds__(256) void wfuse_kernel(const float* __restrict__ W1,
                                                    const float* __restrict__ W2,
                                                    const float* __restrict__ b1,
                                                    const float* __restrict__ b2,
                                                    __hip_bfloat16* __restrict__ wfb,
                                                    float* __restrict__ cb)
{
    __shared__ float sW2[NP * 129];      // [n][oc], stride 129 kills bank conflicts
    __shared__ float sW1[128 * 32];      // [oc][ci]
    int tap = blockIdx.x;                // 0..48
    int cc  = blockIdx.y;                // 0..7
    int tid = threadIdx.x;

    for (int idx = tid; idx < NP * 128; idx += 256) {
        int n = idx >> 7, oc = idx & 127;
        sW2[n * 129 + oc] = (n < NT) ? W2[n * 128 + oc] : 0.0f;
    }
    for (int idx = tid; idx < 128 * 32; idx += 256) {
        int oc = idx >> 5, ci = idx & 31;
        sW1[idx] = W1[((size_t)(oc * C_ + cc * 32 + ci)) * NT + tap];
    }
    __syncthreads();

    int ntile = tid >> 6;
    int l     = tid & 63;
    int n     = ntile * 16 + (l & 15);
    int q     = l >> 4;

    float acc[8] = {0,0,0,0,0,0,0,0};
    for (int oc = 0; oc < 128; ++oc) {
        float w2 = sW2[n * 129 + oc];
        const float* r = &sW1[oc * 32 + q * 8];
        #pragma unroll
        for (int j = 0; j < 8; ++j)
            acc[j] += w2 * r[j];
    }

    short pk[8];
    #pragma unroll
    for (int j = 0; j < 8; ++j) {
        __hip_bfloat16 v = __float2bfloat16(acc[j]);
        pk[j] = *(short*)&v;
    }
    short* dst = (short*)wfb + ((size_t)(tap * 8 + cc) * 4 + ntile) * 512 + l * 8;
    *(bf16x8*)dst = *(bf16x8*)pk;

    // fold cbias here (removes a separate launch): cb[l] = b2[l] + W2[l,:]@b1
    if (tap == 0 && cc == 0 && tid < 64) {
        float a = 0.0f;
        if (tid < NT) {
            a = b2[tid];
            for (int oc = 0; oc < 128; ++oc)
                a += sW2[tid * 129 + oc] * b1[oc];
        }
        cb[tid] = a;
    }
}

// Fused conv implicit GEMM (validated R9): wave tile M64xN64, block M256xN64.
// A from global once per block; B(i,cc) staged in LDS, conflict-free ds_read.
__global__ __launch_bounds__(256) void conv1_mfma5(const __hip_bfloat16* __restrict__ xp,
                                                   const __hip_bfloat16* __restrict__ wfb,
                                                   float* __restrict__ kpart)
{
    __shared__ short sB[28 * 512];        // [j7][nt4][lane64][8] = 28 KB

    const int bid = blockIdx.x;
    const int g   = bid & 7;              // presumed XCD (round-robin dispatch)
    const int kk  = bid >> 3;             // 0..97
    const int s   = (g * 49) >> 3;
    const int cnt = (((g + 1) * 49) >> 3) - s;   // 6 or 7
    const int slice = kk / cnt;           // 0..13 valid
    if (slice >= NSL) return;
    const int mblk = s + (kk - slice * cnt);
    const int m0   = mblk * 256;
    const int i    = slice >> 1;          // tap row 0..6
    const int ch   = slice & 1;           // cc half: cc in [ch*4, ch*4+4)

    const int tid  = threadIdx.x;
    const int lane = tid & 63;
    const int wid  = tid >> 6;            // waveM: wave owns rows m0+wid*64..+63
    const int quad = lane >> 4, l16 = lane & 15;

    const short* xps = (const short*)xp;
    const short* wbs = (const short*)wfb;
    const long CC_STRIDE = (long)B_ * HP_ * HP_ * 32;   // 591,872 elements

    long abase[4];
    #pragma unroll
    for (int mt = 0; mt < 4; ++mt) {
        int m = m0 + wid * 64 + mt * 16 + l16;
        int b = m / HW_; int hw = m - b * HW_;
        int h = hw / W_; int w = hw - h * W_;
        abase[mt] = ((long)(b * HP_ + (h + 2 * i)) * HP_ + w) * 32 + quad * 8;
    }

    f32x4 acc[4][4];
    #pragma unroll
    for (int a = 0; a < 4; ++a)
        #pragma unroll
        for (int b2 = 0; b2 < 4; ++b2) acc[a][b2] = (f32x4){0.f, 0.f, 0.f, 0.f};

    for (int cc4 = 0; cc4 < 4; ++cc4) {
        const int cc = ch * 4 + cc4;
        __syncthreads();                  // guard prev phase's reads vs restage
        // stage B(i,cc): 28 chunks of 512 shorts; wave w does q = w + 4k
        #pragma unroll
        for (int k = 0; k < 7; ++k) {
            int q = wid + 4 * k;          // 0..27
            int j = q >> 2, nt = q & 3;
            const short* src = wbs + ((((long)(i * 7 + j) * 8 + cc) * 4 + nt) << 9) + lane * 8;
            bf16x8 v = *(const bf16x8*)src;
            *(bf16x8*)(&sB[q * 512 + lane * 8]) = v;
        }
        __syncthreads();

        const long aoffc = (long)cc * CC_STRIDE;
        for (int j = 0; j < 7; ++j) {
            const long aoffj = aoffc + (long)j * 64;   // wp += 2 per j
            bf16x8 af[4], bfr[4];
            #pragma unroll
            for (int mt = 0; mt < 4; ++mt)
                af[mt] = *(const bf16x8*)(xps + abase[mt] + aoffj);
            #pragma unroll
            for (int nt = 0; nt < 4; ++nt)
                bfr[nt] = *(const bf16x8*)(&sB[(j * 4 + nt) * 512 + lane * 8]);
            #pragma unroll
            for (int mt = 0; mt < 4; ++mt)
                #pragma unroll
                for (int nt = 0; nt < 4; ++nt)
                    acc[mt][nt] = __builtin_amdgcn_mfma_f32_16x16x32_bf16(
                        af[mt], bfr[nt], acc[mt][nt], 0, 0, 0);
        }
    }

    // Store: C/D layout col(n)=lane&15, row(m)=quad*4+reg (validated)
    #pragma unroll
    for (int mt = 0; mt < 4; ++mt) {
        int mrow = m0 + wid * 64 + mt * 16 + quad * 4;
        #pragma unroll
        for (int nt = 0; nt < 4; ++nt) {
            int n = nt * 16 + l16;
            float* dst = kpart + ((long)slice * M_TOT + mrow) * NP + n;
            #pragma unroll
            for (int r = 0; r < 4; ++r)
                dst[(long)r * NP] = acc[mt][nt][r];
        }
    }
}

// Fold 14 partial-logit slices + cb, softmax over 49, write pixel-major attnP.
// One wave per pixel; lane = logit. Fully coalesced reads/writes. (validated R8)
__global__ __launch_bounds__(256) void attn_fold(const float* __restrict__ kpart,
                                                 const float* __restrict__ cb,
                                                 float* __restrict__ attnP)
{
    int tid  = threadIdx.x;
    int wid  = tid >> 6;
    int lane = tid & 63;
    int pix  = blockIdx.x * 4 + wid;     // < 12544

    const float* kp = kpart + (size_t)pix * NP + lane;
    float v = 0.0f;
    #pragma unroll
    for (int sp = 0; sp < NSL; ++sp)
        v += kp[(size_t)sp * M_TOT * NP];

    float logit = (lane < NT) ? (v + cb[lane]) : -INFINITY;
    float mx = logit;
    for (int s = 32; s > 0; s >>= 1) mx = fmaxf(mx, __shfl_xor(mx, s, 64));
    float e = (lane < NT) ? __expf(logit - mx) : 0.0f;
    float sum = e;
    for (int s = 32; s > 0; s >>= 1) sum += __shfl_xor(sum, s, 64);
    if (lane < NT)
        attnP[(size_t)pix * NT + lane] = e / sum;
}

// Weighted 49-tap gather. R10: granule-major sX layout [i][cg4][wp][c4] so
// the f32x4 main-loop read has lane-granule stride 1 -> conflict-free b128
// (R9 profile: 1.155e7 SQ_LDS_BANK_CONFLICT from the old [i][wp][c16] layout
// whose lane stride of 64 B put all even lanes on the same 4 banks).
__global__ __launch_bounds__(256) void out_kernel4(const float* __restrict__ x,
                                                   const float* __restrict__ attnP,
                                                   float* __restrict__ out)
{
    __shared__ float sX[7 * 4 * HP_ * 4]; // [i][cg4][wp][c4] 30.5 KB
    __shared__ float sA[56 * NT];         // [w][l] 10.7 KB

    int bid = blockIdx.x;                // < 3584
    int g   = bid & 7;                   // presumed XCD
    int s   = bid >> 3;                  // 0..447
    int bh  = g * 28 + (s % 28);         // 28 bh-rows per XCD slot
    int cg  = s / 28;                    // 0..15
    int b   = bh / H_;
    int h   = bh - b * H_;
    int c0  = cg * 16;
    int tid = threadIdx.x;

    for (int idx = tid; idx < 7 * 4 * HP_ * 4; idx += 256)
        sX[idx] = 0.0f;
    __syncthreads();

    {
        const float* ap = attnP + ((size_t)(b * HW_) + h * W_) * NT;
        for (int idx = tid; idx < W_ * NT; idx += 256)
            sA[idx] = ap[idx];
    }
    // stage valid x rows: thread = (c = tid>>4, wg = tid&15); writes are b32
    // at bank (4*(wg%8)+(c&3))%32 within a wave -> exactly 2-way (free).
    {
        int c  = tid >> 4;
        int wg = tid & 15;
        const float* xc = x + (size_t)(b * C_ + c0 + c) * HW_;
        int cgr = c >> 2, ce = c & 3;
        #pragma unroll
        for (int i = 0; i < 7; ++i) {
            int ih = h + 2 * i - 6;
            if (ih < 0 || ih >= H_) continue;
            const float* xr = xc + ih * W_;
            #pragma unroll
            for (int k = 0; k < 4; ++k) {
                int w = wg + 16 * k;
                if (w < W_)
                    sX[(((i * 4 + cgr) * HP_) + (w + 6)) * 4 + ce] = xr[w];
            }
        }
    }
    __syncthreads();

    int lane = tid & 63;
    int wid  = tid >> 6;                 // wave -> channels c0+wid*4 .. +3
    int w    = lane;
    bool active = (w < W_);
    int wc = active ? w : (W_ - 1);

    float aR[NT];
    #pragma unroll
    for (int l = 0; l < NT; ++l)
        aR[l] = sA[wc * NT + l];

    f32x4 acc = (f32x4){0.f, 0.f, 0.f, 0.f};
    #pragma unroll
    for (int i = 0; i < 7; ++i) {
        const float* sXi = &sX[(i * 4 + wid) * HP_ * 4];
        #pragma unroll
        for (int j = 0; j < 7; ++j) {
            // granule index = wc + 2j: lane stride 1 granule -> conflict-free
            f32x4 xv = *(const f32x4*)&sXi[(wc + 2 * j) * 4];
            float a = aR[i * 7 + j];
            acc.x += a * xv.x; acc.y += a * xv.y;
            acc.z += a * xv.z; acc.w += a * xv.w;
        }
    }

    if (active) {
        size_t o = ((size_t)(b * C_ + c0 + wid * 4)) * HW_ + h * W_ + w;
        out[o + 0 * HW_] = acc.x;
        out[o + 1 * HW_] = acc.y;
        out[o + 2 * HW_] = acc.z;
        out[o + 3 * HW_] = acc.w;
    }
}

// ===========================================================================
// FALLBACK PATH (R1, proven): used only if ws_size < fast-path need
// ===========================================================================
__global__ __launch_bounds__(256) void wt_kernel(const float* __restrict__ W1,
                                                 float* __restrict__ wT)
{
    int idx = blockIdx.x * 256 + threadIdx.x;
    int oc = idx & 127;
    int ct = idx >> 7;
    wT[idx] = W1[oc * (C_ * NT) + ct];
}

__global__ __launch_bounds__(256) void conv1_kernel(const float* __restrict__ x,
                                                    const float* __restrict__ wT,
                                                    const float* __restrict__ b1,
                                                    float* __restrict__ k)
{
    int tid = threadIdx.x;
    int w   = tid & 63;
    int ty  = tid >> 6;
    int h   = blockIdx.x * 4 + ty;
    int oc0 = blockIdx.y * 8;
    int b   = blockIdx.z;

    const float* xb = x + (size_t)b * C_ * HW_;
    float acc[8] = {0.f,0.f,0.f,0.f,0.f,0.f,0.f,0.f};

    for (int i = 0; i < 7; ++i) {
        int ih = h + 2 * i - 6;
        if (ih < 0 || ih >= H_) continue;
        for (int j = 0; j < 7; ++j) {
            int iw = w + 2 * j - 6;
            bool v  = (iw >= 0) && (iw < W_);
            float m = v ? 1.0f : 0.0f;
            const float* xr = xb + ih * W_ + (v ? iw : 0);
            const float* wr = wT + (size_t)(i * 7 + j) * OC1 + oc0;
            #pragma unroll 4
            for (int c = 0; c < C_; ++c) {
                float xv = m * xr[(size_t)c * HW_];
                const float4 w0 = *(const float4*)(wr + (size_t)c * NT * OC1);
                const float4 w1 = *(const float4*)(wr + (size_t)c * NT * OC1 + 4);
                acc[0] += xv * w0.x; acc[1] += xv * w0.y;
                acc[2] += xv * w0.z; acc[3] += xv * w0.w;
                acc[4] += xv * w1.x; acc[5] += xv * w1.y;
                acc[6] += xv * w1.z; acc[7] += xv * w1.w;
            }
        }
    }
    if (w < W_) {
        size_t o = ((size_t)(b * OC1 + oc0)) * HW_ + h * W_ + w;
        #pragma unroll
        for (int q = 0; q < 8; ++q)
            k[o + (size_t)q * HW_] = acc[q] + b1[oc0 + q];
    }
}

__global__ __launch_bounds__(256) void attn_kernel(const float* __restrict__ kin,
                                                   const float* __restrict__ W2,
                                                   const float* __restrict__ b2,
                                                   float* __restrict__ attn)
{
    __shared__ float sW2[128 * 49];
    int tid = threadIdx.x;
    for (int idx = tid; idx < 128 * 49; idx += 256) {
        int c = idx / 49, l = idx - c * 49;
        sW2[idx] = W2[l * 128 + c];
    }
    __syncthreads();

    int wid  = tid >> 6;
    int lane = tid & 63;
    int pix  = blockIdx.x * 4 + wid;
    int b    = pix / HW_;
    int hw   = pix - b * HW_;
    int l    = (lane < 49) ? lane : 0;

    const float* kb = kin + (size_t)b * OC1 * HW_ + hw;
    float acc = b2[l];
    #pragma unroll 8
    for (int c = 0; c < 128; ++c)
        acc += kb[(size_t)c * HW_] * sW2[c * 49 + l];

    float logit = (lane < 49) ? acc : -INFINITY;
    float mx = logit;
    for (int s = 32; s > 0; s >>= 1) mx = fmaxf(mx, __shfl_xor(mx, s, 64));
    float e = (lane < 49) ? __expf(logit - mx) : 0.0f;
    float sum = e;
    for (int s = 32; s > 0; s >>= 1) sum += __shfl_xor(sum, s, 64);
    if (lane < 49)
        attn[((size_t)b * NT + lane) * HW_ + hw] = e / sum;
}

__global__ __launch_bounds__(256) void out_kernel(const float* __restrict__ x,
                                                  const float* __restrict__ attn,
                                                  float* __restrict__ out)
{
    int idx = blockIdx.x * 256 + threadIdx.x;
    int w  = idx % 56;
    int t  = idx / 56;
    int h  = t % 56;
    int t2 = t / 56;
    int c  = t2 & 255;
    int b  = t2 >> 8;

    const float* xb = x + (size_t)(b * C_ + c) * HW_;
    const float* ab = attn + (size_t)b * NT * HW_ + h * W_ + w;

    float acc = 0.f;
    #pragma unroll
    for (int i = 0; i < 7; ++i) {
        int ih = h + 2 * i - 6;
        bool hv = (ih >= 0) && (ih < H_);
        #pragma unroll
        for (int j = 0; j < 7; ++j) {
            int iw = w + 2 * j - 6;
            bool v  = hv && (iw >= 0) && (iw < W_);
            float m = v ? 1.0f : 0.0f;
            int off = v ? (ih * W_ + iw) : 0;
            acc += (m * xb[off]) * ab[(size_t)(i * 7 + j) * HW_];
        }
    }
    out[idx] = acc;
}

// ===========================================================================
extern "C" void kernel_launch(void* const* d_in, const int* in_sizes, int n_in,
                              void* d_out, int out_size, void* d_ws, size_t ws_size,
                              hipStream_t stream)
{
    const float* x  = (const float*)d_in[0];
    const float* W1 = (const float*)d_in[1];
    const float* b1 = (const float*)d_in[2];
    const float* W2 = (const float*)d_in[3];
    const float* b2 = (const float*)d_in[4];
    float* out = (float*)d_out;

    // fast-path ws layout (bytes)
    const size_t xp_b    = (size_t)B_ * HP_ * HP_ * 256 * 2;        //  9,469,952
    const size_t wfb_b   = (size_t)NT * 8 * 4 * 64 * 8 * 2;         //  1,605,632
    const size_t kpart_b = (size_t)NSL * M_TOT * NP * 4;            // 44,957,696
    const size_t attn_b  = (size_t)M_TOT * NT * 4;                  //  2,458,624
    const size_t cb_b    = 256;
    const size_t need = xp_b + wfb_b + kpart_b + attn_b + cb_b;     // ~58.5 MB

    if (ws_size >= need) {
        char* base = (char*)d_ws;
        __hip_bfloat16* xp  = (__hip_bfloat16*)base;
        __hip_bfloat16* wfb = (__hip_bfloat16*)(base + xp_b);
        float* kpart = (float*)(base + xp_b + wfb_b);
        float* attnP = (float*)(base + xp_b + wfb_b + kpart_b);
        float* cb    = (float*)(base + xp_b + wfb_b + kpart_b + attn_b);

        xpack2_kernel<<<2176, 256, 0, stream>>>(x, xp);
        wfuse_kernel <<<dim3(49, 8), 256, 0, stream>>>(W1, W2, b1, b2, wfb, cb);
        conv1_mfma5  <<<784, 256, 0, stream>>>(xp, wfb, kpart);
        attn_fold    <<<3136, 256, 0, stream>>>(kpart, cb, attnP);
        out_kernel4  <<<3584, 256, 0, stream>>>(x, attnP, out);
    } else {
        // R1 fallback (~14.6 MB)
        float* wT   = (float*)d_ws;
        float* kbuf = wT + 1605632;
        float* attn = kbuf + 1605632;
        wt_kernel   <<<6272, 256, 0, stream>>>(W1, wT);
        conv1_kernel<<<dim3(14, 16, 4), 256, 0, stream>>>(x, wT, b1, kbuf);
        attn_kernel <<<3136, 256, 0, stream>>>(kbuf, W2, b2, attn);
        out_kernel  <<<12544, 256, 0, stream>>>(x, attn, out);
    }
}

// Round 11
// 183.393 us; speedup vs baseline: 1.1264x; 1.0002x over previous
//
#include <hip/hip_runtime.h>
#include <hip/hip_bf16.h>
#include <math.h>

#define B_   4
#define C_   256
#define H_   56
#define W_   56
#define HW_  3136
#define OC1  128
#define NT   49
#define NP   64          // padded logit count
#define HP_  68          // 56 + 2*6 padded
#define M_TOT 12544      // B_*HW_
#define NSL  28          // K-split slices: 7 tap-rows x 4 cc-pairs

typedef __attribute__((ext_vector_type(8))) short bf16x8;
typedef __attribute__((ext_vector_type(4))) float f32x4;

// ===========================================================================
// FAST PATH: fused-weight bf16 MFMA implicit GEMM (conv2 folded into conv1)
// logits = conv(x, Wf) + cb,  Wf[l,c,tap] = sum_oc W2[l,oc]*W1[oc,c,tap]
// xp2 layout: [cc 8][b 4][hp 68][wp 68][ci 32] bf16   (validated R4-R10)
// wfb layout: [tap 49][cc 8][ntile 4][lane 64][j 8] bf16 fragment order
// kpart: bf16 [slice 28][m 12544][n 64]  (bf16 so 28 slices fit ws)
// ===========================================================================

// Pack x (f32 NCHW) -> xp2, zero borders. One block per (cc, b, hp). (validated)
__global__ __launch_bounds__(256) void xpack2_kernel(const float* __restrict__ x,
                                                     __hip_bfloat16* __restrict__ xp)
{
    __shared__ short tile[HP_ * 32];     // [wp][ci]
    int bid = blockIdx.x;                // < 8*4*68 = 2176
    int cc = bid / (B_ * HP_);
    int r  = bid - cc * (B_ * HP_);
    int b  = r / HP_;
    int hp = r - b * HP_;
    int h  = hp - 6;
    int tid = threadIdx.x;

    if (h < 0 || h >= H_) {
        for (int idx = tid; idx < HP_ * 32; idx += 256) tile[idx] = 0;
    } else {
        int ci = tid >> 3;               // 0..31
        int wg = tid & 7;                // 0..7
        const float* xr = x + ((size_t)(b * C_ + cc * 32 + ci) * H_ + h) * W_;
        #pragma unroll
        for (int k = 0; k < 7; ++k) {
            int w = wg + 8 * k;          // covers 0..55 exactly
            __hip_bfloat16 v = __float2bfloat16(xr[w]);
            tile[(w + 6) * 32 + ci] = *(short*)&v;
        }
        for (int idx = tid; idx < 384; idx += 256) {
            int wp = idx >> 5;           // 0..11
            int wz = (wp < 6) ? wp : (wp + 56);
            tile[wz * 32 + (idx & 31)] = 0;
        }
    }
    __syncthreads();
    short* outp = (short*)xp + ((size_t)((cc * B_ + b) * HP_ + hp) * HP_) * 32;
    for (int idx = tid; idx < 272; idx += 256)
        *(bf16x8*)(outp + idx * 8) = *(bf16x8*)(tile + idx * 8);
}

// Fused-weight pack (validated R7-R10) + cbias folded into block (0,0).
__global__ __launch_bounds__(256) void wfuse_kernel(const float* __restrict__ W1,
                                                    const float* __restrict__ W2,
                                                    const float* __restrict__ b1,
                                                    const float* __restrict__ b2,
                                                    __hip_bfloat16* __restrict__ wfb,
                                                    float* __restrict__ cb)
{
    __shared__ float sW2[NP * 129];      // [n][oc], stride 129 kills bank conflicts
    __shared__ float sW1[128 * 32];      // [oc][ci]
    int tap = blockIdx.x;                // 0..48
    int cc  = blockIdx.y;                // 0..7
    int tid = threadIdx.x;

    for (int idx = tid; idx < NP * 128; idx += 256) {
        int n = idx >> 7, oc = idx & 127;
        sW2[n * 129 + oc] = (n < NT) ? W2[n * 128 + oc] : 0.0f;
    }
    for (int idx = tid; idx < 128 * 32; idx += 256) {
        int oc = idx >> 5, ci = idx & 31;
        sW1[idx] = W1[((size_t)(oc * C_ + cc * 32 + ci)) * NT + tap];
    }
    __syncthreads();

    int ntile = tid >> 6;
    int l     = tid & 63;
    int n     = ntile * 16 + (l & 15);
    int q     = l >> 4;

    float acc[8] = {0,0,0,0,0,0,0,0};
    for (int oc = 0; oc < 128; ++oc) {
        float w2 = sW2[n * 129 + oc];
        const float* r = &sW1[oc * 32 + q * 8];
        #pragma unroll
        for (int j = 0; j < 8; ++j)
            acc[j] += w2 * r[j];
    }

    short pk[8];
    #pragma unroll
    for (int j = 0; j < 8; ++j) {
        __hip_bfloat16 v = __float2bfloat16(acc[j]);
        pk[j] = *(short*)&v;
    }
    short* dst = (short*)wfb + ((size_t)(tap * 8 + cc) * 4 + ntile) * 512 + l * 8;
    *(bf16x8*)dst = *(bf16x8*)pk;

    if (tap == 0 && cc == 0 && tid < 64) {
        float a = 0.0f;
        if (tid < NT) {
            a = b2[tid];
            for (int oc = 0; oc < 128; ++oc)
                a += sW2[tid * 129 + oc] * b1[oc];
        }
        cb[tid] = a;
    }
}

// Fused conv implicit GEMM (R11): R9/R10 structure (wave M64xN64, block
// M256xN64, B in LDS, A once from global) but K-split x2 finer: each block
// = (tap-row i, cc-PAIR) -> NSL=28 slices, 1372 valid blocks (~5.4/CU),
// matching the 5-block LDS residency limit (R10's grid gave only 2.7/CU ->
// 11% occupancy). kpart written as bf16 so 28 slices fit the ws budget.
__global__ __launch_bounds__(256) void conv1_mfma6(const __hip_bfloat16* __restrict__ xp,
                                                   const __hip_bfloat16* __restrict__ wfb,
                                                   __hip_bfloat16* __restrict__ kpart)
{
    __shared__ short sB[28 * 512];        // [j7][nt4][lane64][8] = 28 KB

    const int bid = blockIdx.x;
    const int g   = bid & 7;              // presumed XCD (round-robin dispatch)
    const int kk  = bid >> 3;             // 0..195
    const int s   = (g * 49) >> 3;
    const int cnt = (((g + 1) * 49) >> 3) - s;   // 6 or 7
    const int slice = kk / cnt;           // 0..27 valid
    if (slice >= NSL) return;
    const int mblk = s + (kk - slice * cnt);
    const int m0   = mblk * 256;
    const int i    = slice >> 2;          // tap row 0..6
    const int chq  = slice & 3;           // cc pair: cc in {chq*2, chq*2+1}

    const int tid  = threadIdx.x;
    const int lane = tid & 63;
    const int wid  = tid >> 6;            // waveM: wave owns rows m0+wid*64..+63
    const int quad = lane >> 4, l16 = lane & 15;

    const short* xps = (const short*)xp;
    const short* wbs = (const short*)wfb;
    const long CC_STRIDE = (long)B_ * HP_ * HP_ * 32;   // 591,872 elements

    long abase[4];
    #pragma unroll
    for (int mt = 0; mt < 4; ++mt) {
        int m = m0 + wid * 64 + mt * 16 + l16;
        int b = m / HW_; int hw = m - b * HW_;
        int h = hw / W_; int w = hw - h * W_;
        abase[mt] = ((long)(b * HP_ + (h + 2 * i)) * HP_ + w) * 32 + quad * 8;
    }

    f32x4 acc[4][4];
    #pragma unroll
    for (int a = 0; a < 4; ++a)
        #pragma unroll
        for (int b2 = 0; b2 < 4; ++b2) acc[a][b2] = (f32x4){0.f, 0.f, 0.f, 0.f};

    for (int ph = 0; ph < 2; ++ph) {
        const int cc = chq * 2 + ph;
        __syncthreads();                  // guard prev phase's reads vs restage
        // stage B(i,cc): 28 chunks of 512 shorts; wave w does q = w + 4k
        #pragma unroll
        for (int k = 0; k < 7; ++k) {
            int q = wid + 4 * k;          // 0..27
            int j = q >> 2, nt = q & 3;
            const short* src = wbs + ((((long)(i * 7 + j) * 8 + cc) * 4 + nt) << 9) + lane * 8;
            bf16x8 v = *(const bf16x8*)src;
            *(bf16x8*)(&sB[q * 512 + lane * 8]) = v;
        }
        __syncthreads();

        const long aoffc = (long)cc * CC_STRIDE;
        for (int j = 0; j < 7; ++j) {
            const long aoffj = aoffc + (long)j * 64;   // wp += 2 per j
            bf16x8 af[4], bfr[4];
            #pragma unroll
            for (int mt = 0; mt < 4; ++mt)
                af[mt] = *(const bf16x8*)(xps + abase[mt] + aoffj);
            #pragma unroll
            for (int nt = 0; nt < 4; ++nt)
                bfr[nt] = *(const bf16x8*)(&sB[(j * 4 + nt) * 512 + lane * 8]);
            #pragma unroll
            for (int mt = 0; mt < 4; ++mt)
                #pragma unroll
                for (int nt = 0; nt < 4; ++nt)
                    acc[mt][nt] = __builtin_amdgcn_mfma_f32_16x16x32_bf16(
                        af[mt], bfr[nt], acc[mt][nt], 0, 0, 0);
        }
    }

    // Store bf16: C/D layout col(n)=lane&15, row(m)=quad*4+reg (validated)
    __hip_bfloat16* kb = kpart;
    #pragma unroll
    for (int mt = 0; mt < 4; ++mt) {
        int mrow = m0 + wid * 64 + mt * 16 + quad * 4;
        #pragma unroll
        for (int nt = 0; nt < 4; ++nt) {
            int n = nt * 16 + l16;
            __hip_bfloat16* dst = kb + ((long)slice * M_TOT + mrow) * NP + n;
            #pragma unroll
            for (int r = 0; r < 4; ++r)
                dst[(long)r * NP] = __float2bfloat16(acc[mt][nt][r]);
        }
    }
}

// Fold 28 bf16 partial-logit slices + cb, softmax over 49 -> pixel-major attnP.
// One wave per pixel; lane = logit. Coalesced 128 B/wave/slice reads.
__global__ __launch_bounds__(256) void attn_fold2(const unsigned short* __restrict__ kpart,
                                                  const float* __restrict__ cb,
                                                  float* __restrict__ attnP)
{
    int tid  = threadIdx.x;
    int wid  = tid >> 6;
    int lane = tid & 63;
    int pix  = blockIdx.x * 4 + wid;     // < 12544

    const unsigned short* kp = kpart + (size_t)pix * NP + lane;
    float v = 0.0f;
    #pragma unroll
    for (int sp = 0; sp < NSL; ++sp) {
        unsigned int u = (unsigned int)kp[(size_t)sp * M_TOT * NP] << 16;
        v += __uint_as_float(u);
    }

    float logit = (lane < NT) ? (v + cb[lane]) : -INFINITY;
    float mx = logit;
    for (int s = 32; s > 0; s >>= 1) mx = fmaxf(mx, __shfl_xor(mx, s, 64));
    float e = (lane < NT) ? __expf(logit - mx) : 0.0f;
    float sum = e;
    for (int s = 32; s > 0; s >>= 1) sum += __shfl_xor(sum, s, 64);
    if (lane < NT)
        attnP[(size_t)pix * NT + lane] = e / sum;
}

// Weighted 49-tap gather (validated R10): granule-major sX [i][cg4][wp][c4]
// -> conflict-free b128 main loop; XCD-swizzled bh blocks.
__global__ __launch_bounds__(256) void out_kernel4(const float* __restrict__ x,
                                                   const float* __restrict__ attnP,
                                                   float* __restrict__ out)
{
    __shared__ float sX[7 * 4 * HP_ * 4]; // [i][cg4][wp][c4] 30.5 KB
    __shared__ float sA[56 * NT];         // [w][l] 10.7 KB

    int bid = blockIdx.x;                // < 3584
    int g   = bid & 7;                   // presumed XCD
    int s   = bid >> 3;                  // 0..447
    int bh  = g * 28 + (s % 28);         // 28 bh-rows per XCD slot
    int cg  = s / 28;                    // 0..15
    int b   = bh / H_;
    int h   = bh - b * H_;
    int c0  = cg * 16;
    int tid = threadIdx.x;

    for (int idx = tid; idx < 7 * 4 * HP_ * 4; idx += 256)
        sX[idx] = 0.0f;
    __syncthreads();

    {
        const float* ap = attnP + ((size_t)(b * HW_) + h * W_) * NT;
        for (int idx = tid; idx < W_ * NT; idx += 256)
            sA[idx] = ap[idx];
    }
    {
        int c  = tid >> 4;
        int wg = tid & 15;
        const float* xc = x + (size_t)(b * C_ + c0 + c) * HW_;
        int cgr = c >> 2, ce = c & 3;
        #pragma unroll
        for (int i = 0; i < 7; ++i) {
            int ih = h + 2 * i - 6;
            if (ih < 0 || ih >= H_) continue;
            const float* xr = xc + ih * W_;
            #pragma unroll
            for (int k = 0; k < 4; ++k) {
                int w = wg + 16 * k;
                if (w < W_)
                    sX[(((i * 4 + cgr) * HP_) + (w + 6)) * 4 + ce] = xr[w];
            }
        }
    }
    __syncthreads();

    int lane = tid & 63;
    int wid  = tid >> 6;                 // wave -> channels c0+wid*4 .. +3
    int w    = lane;
    bool active = (w < W_);
    int wc = active ? w : (W_ - 1);

    float aR[NT];
    #pragma unroll
    for (int l = 0; l < NT; ++l)
        aR[l] = sA[wc * NT + l];

    f32x4 acc = (f32x4){0.f, 0.f, 0.f, 0.f};
    #pragma unroll
    for (int i = 0; i < 7; ++i) {
        const float* sXi = &sX[(i * 4 + wid) * HP_ * 4];
        #pragma unroll
        for (int j = 0; j < 7; ++j) {
            f32x4 xv = *(const f32x4*)&sXi[(wc + 2 * j) * 4];
            float a = aR[i * 7 + j];
            acc.x += a * xv.x; acc.y += a * xv.y;
            acc.z += a * xv.z; acc.w += a * xv.w;
        }
    }

    if (active) {
        size_t o = ((size_t)(b * C_ + c0 + wid * 4)) * HW_ + h * W_ + w;
        out[o + 0 * HW_] = acc.x;
        out[o + 1 * HW_] = acc.y;
        out[o + 2 * HW_] = acc.z;
        out[o + 3 * HW_] = acc.w;
    }
}

// ===========================================================================
// FALLBACK PATH (R1, proven): used only if ws_size < fast-path need
// ===========================================================================
__global__ __launch_bounds__(256) void wt_kernel(const float* __restrict__ W1,
                                                 float* __restrict__ wT)
{
    int idx = blockIdx.x * 256 + threadIdx.x;
    int oc = idx & 127;
    int ct = idx >> 7;
    wT[idx] = W1[oc * (C_ * NT) + ct];
}

__global__ __launch_bounds__(256) void conv1_kernel(const float* __restrict__ x,
                                                    const float* __restrict__ wT,
                                                    const float* __restrict__ b1,
                                                    float* __restrict__ k)
{
    int tid = threadIdx.x;
    int w   = tid & 63;
    int ty  = tid >> 6;
    int h   = blockIdx.x * 4 + ty;
    int oc0 = blockIdx.y * 8;
    int b   = blockIdx.z;

    const float* xb = x + (size_t)b * C_ * HW_;
    float acc[8] = {0.f,0.f,0.f,0.f,0.f,0.f,0.f,0.f};

    for (int i = 0; i < 7; ++i) {
        int ih = h + 2 * i - 6;
        if (ih < 0 || ih >= H_) continue;
        for (int j = 0; j < 7; ++j) {
            int iw = w + 2 * j - 6;
            bool v  = (iw >= 0) && (iw < W_);
            float m = v ? 1.0f : 0.0f;
            const float* xr = xb + ih * W_ + (v ? iw : 0);
            const float* wr = wT + (size_t)(i * 7 + j) * OC1 + oc0;
            #pragma unroll 4
            for (int c = 0; c < C_; ++c) {
                float xv = m * xr[(size_t)c * HW_];
                const float4 w0 = *(const float4*)(wr + (size_t)c * NT * OC1);
                const float4 w1 = *(const float4*)(wr + (size_t)c * NT * OC1 + 4);
                acc[0] += xv * w0.x; acc[1] += xv * w0.y;
                acc[2] += xv * w0.z; acc[3] += xv * w0.w;
                acc[4] += xv * w1.x; acc[5] += xv * w1.y;
                acc[6] += xv * w1.z; acc[7] += xv * w1.w;
            }
        }
    }
    if (w < W_) {
        size_t o = ((size_t)(b * OC1 + oc0)) * HW_ + h * W_ + w;
        #pragma unroll
        for (int q = 0; q < 8; ++q)
            k[o + (size_t)q * HW_] = acc[q] + b1[oc0 + q];
    }
}

__global__ __launch_bounds__(256) void attn_kernel(const float* __restrict__ kin,
                                                   const float* __restrict__ W2,
                                                   const float* __restrict__ b2,
                                                   float* __restrict__ attn)
{
    __shared__ float sW2[128 * 49];
    int tid = threadIdx.x;
    for (int idx = tid; idx < 128 * 49; idx += 256) {
        int c = idx / 49, l = idx - c * 49;
        sW2[idx] = W2[l * 128 + c];
    }
    __syncthreads();

    int wid  = tid >> 6;
    int lane = tid & 63;
    int pix  = blockIdx.x * 4 + wid;
    int b    = pix / HW_;
    int hw   = pix - b * HW_;
    int l    = (lane < 49) ? lane : 0;

    const float* kb = kin + (size_t)b * OC1 * HW_ + hw;
    float acc = b2[l];
    #pragma unroll 8
    for (int c = 0; c < 128; ++c)
        acc += kb[(size_t)c * HW_] * sW2[c * 49 + l];

    float logit = (lane < 49) ? acc : -INFINITY;
    float mx = logit;
    for (int s = 32; s > 0; s >>= 1) mx = fmaxf(mx, __shfl_xor(mx, s, 64));
    float e = (lane < 49) ? __expf(logit - mx) : 0.0f;
    float sum = e;
    for (int s = 32; s > 0; s >>= 1) sum += __shfl_xor(sum, s, 64);
    if (lane < 49)
        attn[((size_t)b * NT + lane) * HW_ + hw] = e / sum;
}

__global__ __launch_bounds__(256) void out_kernel(const float* __restrict__ x,
                                                  const float* __restrict__ attn,
                                                  float* __restrict__ out)
{
    int idx = blockIdx.x * 256 + threadIdx.x;
    int w  = idx % 56;
    int t  = idx / 56;
    int h  = t % 56;
    int t2 = t / 56;
    int c  = t2 & 255;
    int b  = t2 >> 8;

    const float* xb = x + (size_t)(b * C_ + c) * HW_;
    const float* ab = attn + (size_t)b * NT * HW_ + h * W_ + w;

    float acc = 0.f;
    #pragma unroll
    for (int i = 0; i < 7; ++i) {
        int ih = h + 2 * i - 6;
        bool hv = (ih >= 0) && (ih < H_);
        #pragma unroll
        for (int j = 0; j < 7; ++j) {
            int iw = w + 2 * j - 6;
            bool v  = hv && (iw >= 0) && (iw < W_);
            float m = v ? 1.0f : 0.0f;
            int off = v ? (ih * W_ + iw) : 0;
            acc += (m * xb[off]) * ab[(size_t)(i * 7 + j) * HW_];
        }
    }
    out[idx] = acc;
}

// ===========================================================================
extern "C" void kernel_launch(void* const* d_in, const int* in_sizes, int n_in,
                              void* d_out, int out_size, void* d_ws, size_t ws_size,
                              hipStream_t stream)
{
    const float* x  = (const float*)d_in[0];
    const float* W1 = (const float*)d_in[1];
    const float* b1 = (const float*)d_in[2];
    const float* W2 = (const float*)d_in[3];
    const float* b2 = (const float*)d_in[4];
    float* out = (float*)d_out;

    // fast-path ws layout (bytes)
    const size_t xp_b    = (size_t)B_ * HP_ * HP_ * 256 * 2;        //  9,469,952
    const size_t wfb_b   = (size_t)NT * 8 * 4 * 64 * 8 * 2;         //  1,605,632
    const size_t kpart_b = (size_t)NSL * M_TOT * NP * 2;            // 44,957,696 (bf16)
    const size_t attn_b  = (size_t)M_TOT * NT * 4;                  //  2,458,624
    const size_t cb_b    = 256;
    const size_t need = xp_b + wfb_b + kpart_b + attn_b + cb_b;     // ~58.5 MB

    if (ws_size >= need) {
        char* base = (char*)d_ws;
        __hip_bfloat16* xp    = (__hip_bfloat16*)base;
        __hip_bfloat16* wfb   = (__hip_bfloat16*)(base + xp_b);
        __hip_bfloat16* kpart = (__hip_bfloat16*)(base + xp_b + wfb_b);
        float* attnP = (float*)(base + xp_b + wfb_b + kpart_b);
        float* cb    = (float*)(base + xp_b + wfb_b + kpart_b + attn_b);

        xpack2_kernel<<<2176, 256, 0, stream>>>(x, xp);
        wfuse_kernel <<<dim3(49, 8), 256, 0, stream>>>(W1, W2, b1, b2, wfb, cb);
        conv1_mfma6  <<<1568, 256, 0, stream>>>(xp, wfb, kpart);
        attn_fold2   <<<3136, 256, 0, stream>>>((const unsigned short*)kpart, cb, attnP);
        out_kernel4  <<<3584, 256, 0, stream>>>(x, attnP, out);
    } else {
        // R1 fallback (~14.6 MB)
        float* wT   = (float*)d_ws;
        float* kbuf = wT + 1605632;
        float* attn = kbuf + 1605632;
        wt_kernel   <<<6272, 256, 0, stream>>>(W1, wT);
        conv1_kernel<<<dim3(14, 16, 4), 256, 0, stream>>>(x, wT, b1, kbuf);
        attn_kernel <<<3136, 256, 0, stream>>>(kbuf, W2, b2, attn);
        out_kernel  <<<12544, 256, 0, stream>>>(x, attn, out);
    }
}

// Round 12
// 179.274 us; speedup vs baseline: 1.1523x; 1.0230x over previous
//
#include <hip/hip_runtime.h>
#include <hip/hip_bf16.h>
#include <math.h>

#define B_   4
#define C_   256
#define H_   56
#define W_   56
#define HW_  3136
#define OC1  128
#define NT   49
#define NP   64          // padded logit count
#define HP_  68          // 56 + 2*6 padded
#define M_TOT 12544      // B_*HW_
#define NSL  14          // K-split slices: 7 tap-rows x 2 cc-halves (4 cc each)

typedef __attribute__((ext_vector_type(8))) short bf16x8;
typedef __attribute__((ext_vector_type(4))) float f32x4;

// ===========================================================================
// FAST PATH: fused-weight bf16 MFMA implicit GEMM (conv2 folded into conv1)
// logits = conv(x, Wf) + cb,  Wf[l,c,tap] = sum_oc W2[l,oc]*W1[oc,c,tap]
// xp2 layout: [cc 8][b 4][hp 68][wp 68][ci 32] bf16   (validated R4-R11)
// wfb layout: [tap 49][cc 8][ntile 4][lane 64][j 8] bf16 fragment order
// kpart: bf16 [slice 14][m 12544][n 64]
// ===========================================================================

// Pack x (f32 NCHW) -> xp2, zero borders. One block per (cc, b, hp). (validated)
__global__ __launch_bounds__(256) void xpack2_kernel(const float* __restrict__ x,
                                                     __hip_bfloat16* __restrict__ xp)
{
    __shared__ short tile[HP_ * 32];     // [wp][ci]
    int bid = blockIdx.x;                // < 8*4*68 = 2176
    int cc = bid / (B_ * HP_);
    int r  = bid - cc * (B_ * HP_);
    int b  = r / HP_;
    int hp = r - b * HP_;
    int h  = hp - 6;
    int tid = threadIdx.x;

    if (h < 0 || h >= H_) {
        for (int idx = tid; idx < HP_ * 32; idx += 256) tile[idx] = 0;
    } else {
        int ci = tid >> 3;               // 0..31
        int wg = tid & 7;                // 0..7
        const float* xr = x + ((size_t)(b * C_ + cc * 32 + ci) * H_ + h) * W_;
        #pragma unroll
        for (int k = 0; k < 7; ++k) {
            int w = wg + 8 * k;          // covers 0..55 exactly
            __hip_bfloat16 v = __float2bfloat16(xr[w]);
            tile[(w + 6) * 32 + ci] = *(short*)&v;
        }
        for (int idx = tid; idx < 384; idx += 256) {
            int wp = idx >> 5;           // 0..11
            int wz = (wp < 6) ? wp : (wp + 56);
            tile[wz * 32 + (idx & 31)] = 0;
        }
    }
    __syncthreads();
    short* outp = (short*)xp + ((size_t)((cc * B_ + b) * HP_ + hp) * HP_) * 32;
    for (int idx = tid; idx < 272; idx += 256)
        *(bf16x8*)(outp + idx * 8) = *(bf16x8*)(tile + idx * 8);
}

// Fused-weight pack (validated R7-R11) + cbias folded into block (0,0).
__global__ __launch_bounds__(256) void wfuse_kernel(const float* __restrict__ W1,
                                                    const float* __restrict__ W2,
                                                    const float* __restrict__ b1,
                                                    const float* __restrict__ b2,
                                                    __hip_bfloat16* __restrict__ wfb,
                                                    float* __restrict__ cb)
{
    __shared__ float sW2[NP * 129];      // [n][oc], stride 129 kills bank conflicts
    __shared__ float sW1[128 * 32];      // [oc][ci]
    int tap = blockIdx.x;                // 0..48
    int cc  = blockIdx.y;                // 0..7
    int tid = threadIdx.x;

    for (int idx = tid; idx < NP * 128; idx += 256) {
        int n = idx >> 7, oc = idx & 127;
        sW2[n * 129 + oc] = (n < NT) ? W2[n * 128 + oc] : 0.0f;
    }
    for (int idx = tid; idx < 128 * 32; idx += 256) {
        int oc = idx >> 5, ci = idx & 31;
        sW1[idx] = W1[((size_t)(oc * C_ + cc * 32 + ci)) * NT + tap];
    }
    __syncthreads();

    int ntile = tid >> 6;
    int l     = tid & 63;
    int n     = ntile * 16 + (l & 15);
    int q     = l >> 4;

    float acc[8] = {0,0,0,0,0,0,0,0};
    for (int oc = 0; oc < 128; ++oc) {
        float w2 = sW2[n * 129 + oc];
        const float* r = &sW1[oc * 32 + q * 8];
        #pragma unroll
        for (int j = 0; j < 8; ++j)
            acc[j] += w2 * r[j];
    }

    short pk[8];
    #pragma unroll
    for (int j = 0; j < 8; ++j) {
        __hip_bfloat16 v = __float2bfloat16(acc[j]);
        pk[j] = *(short*)&v;
    }
    short* dst = (short*)wfb + ((size_t)(tap * 8 + cc) * 4 + ntile) * 512 + l * 8;
    *(bf16x8*)dst = *(bf16x8*)pk;

    if (tap == 0 && cc == 0 && tid < 64) {
        float a = 0.0f;
        if (tid < NT) {
            a = b2[tid];
            for (int oc = 0; oc < 128; ++oc)
                a += sW2[tid * 129 + oc] * b1[oc];
        }
        cb[tid] = a;
    }
}

// Fused conv implicit GEMM (R12): R9 geometry (wave M64xN64, block M256xN64,
// B in LDS) + phase-batched A-loads: per cc-phase, ALL 28 A-frags (7j x 4mt)
// are issued before any MFMA consumes them, in issue order -> compiler emits
// rolling vmcnt (never a full drain inside the phase). Attacks the
// latency-serialized j-loop that kept R7-R11 at 45-57 us with all pipes idle.
// ~210 VGPR -> 2 waves/SIMD: fewer waves, far more ILP per wave.
__global__ __launch_bounds__(256) void conv1_mfma7(const __hip_bfloat16* __restrict__ xp,
                                                   const __hip_bfloat16* __restrict__ wfb,
                                                   __hip_bfloat16* __restrict__ kpart)
{
    __shared__ short sB[28 * 512];        // [j7][nt4][lane64][8] = 28 KB

    const int bid = blockIdx.x;
    const int g   = bid & 7;              // presumed XCD (round-robin dispatch)
    const int kk  = bid >> 3;             // 0..97
    const int s   = (g * 49) >> 3;
    const int cnt = (((g + 1) * 49) >> 3) - s;   // 6 or 7
    const int slice = kk / cnt;           // 0..13 valid
    if (slice >= NSL) return;
    const int mblk = s + (kk - slice * cnt);
    const int m0   = mblk * 256;
    const int i    = slice >> 1;          // tap row 0..6
    const int ch   = slice & 1;           // cc half: cc in [ch*4, ch*4+4)

    const int tid  = threadIdx.x;
    const int lane = tid & 63;
    const int wid  = tid >> 6;            // waveM: wave owns rows m0+wid*64..+63
    const int quad = lane >> 4, l16 = lane & 15;

    const short* xps = (const short*)xp;
    const short* wbs = (const short*)wfb;
    const long CC_STRIDE = (long)B_ * HP_ * HP_ * 32;   // 591,872 elements

    long abase[4];
    #pragma unroll
    for (int mt = 0; mt < 4; ++mt) {
        int m = m0 + wid * 64 + mt * 16 + l16;
        int b = m / HW_; int hw = m - b * HW_;
        int h = hw / W_; int w = hw - h * W_;
        abase[mt] = ((long)(b * HP_ + (h + 2 * i)) * HP_ + w) * 32 + quad * 8;
    }

    f32x4 acc[4][4];
    #pragma unroll
    for (int a = 0; a < 4; ++a)
        #pragma unroll
        for (int b2 = 0; b2 < 4; ++b2) acc[a][b2] = (f32x4){0.f, 0.f, 0.f, 0.f};

    #pragma unroll
    for (int cc4 = 0; cc4 < 4; ++cc4) {
        const int cc = ch * 4 + cc4;
        __syncthreads();                  // guard prev phase's reads vs restage
        // stage B(i,cc): 28 chunks of 512 shorts; wave w does q = w + 4k
        #pragma unroll
        for (int k = 0; k < 7; ++k) {
            int q = wid + 4 * k;          // 0..27
            int j = q >> 2, nt = q & 3;
            const short* src = wbs + ((((long)(i * 7 + j) * 8 + cc) * 4 + nt) << 9) + lane * 8;
            bf16x8 v = *(const bf16x8*)src;
            *(bf16x8*)(&sB[q * 512 + lane * 8]) = v;
        }
        __syncthreads();

        const long aoffc = (long)cc * CC_STRIDE;
        // batch-issue the whole phase's A loads (28 frags in flight)
        bf16x8 A[7][4];
        #pragma unroll
        for (int j = 0; j < 7; ++j)
            #pragma unroll
            for (int mt = 0; mt < 4; ++mt)
                A[j][mt] = *(const bf16x8*)(xps + abase[mt] + aoffc + (long)j * 64);
        // consume in issue order -> rolling vmcnt
        #pragma unroll
        for (int j = 0; j < 7; ++j) {
            bf16x8 bfr[4];
            #pragma unroll
            for (int nt = 0; nt < 4; ++nt)
                bfr[nt] = *(const bf16x8*)(&sB[(j * 4 + nt) * 512 + lane * 8]);
            #pragma unroll
            for (int mt = 0; mt < 4; ++mt)
                #pragma unroll
                for (int nt = 0; nt < 4; ++nt)
                    acc[mt][nt] = __builtin_amdgcn_mfma_f32_16x16x32_bf16(
                        A[j][mt], bfr[nt], acc[mt][nt], 0, 0, 0);
        }
    }

    // Store bf16: C/D layout col(n)=lane&15, row(m)=quad*4+reg (validated)
    #pragma unroll
    for (int mt = 0; mt < 4; ++mt) {
        int mrow = m0 + wid * 64 + mt * 16 + quad * 4;
        #pragma unroll
        for (int nt = 0; nt < 4; ++nt) {
            int n = nt * 16 + l16;
            __hip_bfloat16* dst = kpart + ((long)slice * M_TOT + mrow) * NP + n;
            #pragma unroll
            for (int r = 0; r < 4; ++r)
                dst[(long)r * NP] = __float2bfloat16(acc[mt][nt][r]);
        }
    }
}

// Fold 14 bf16 partial-logit slices + cb, softmax over 49 -> pixel-major attnP.
// One wave per pixel; lane = logit. Coalesced 128 B/wave/slice reads.
__global__ __launch_bounds__(256) void attn_fold2(const unsigned short* __restrict__ kpart,
                                                  const float* __restrict__ cb,
                                                  float* __restrict__ attnP)
{
    int tid  = threadIdx.x;
    int wid  = tid >> 6;
    int lane = tid & 63;
    int pix  = blockIdx.x * 4 + wid;     // < 12544

    const unsigned short* kp = kpart + (size_t)pix * NP + lane;
    float v = 0.0f;
    #pragma unroll
    for (int sp = 0; sp < NSL; ++sp) {
        unsigned int u = (unsigned int)kp[(size_t)sp * M_TOT * NP] << 16;
        v += __uint_as_float(u);
    }

    float logit = (lane < NT) ? (v + cb[lane]) : -INFINITY;
    float mx = logit;
    for (int s = 32; s > 0; s >>= 1) mx = fmaxf(mx, __shfl_xor(mx, s, 64));
    float e = (lane < NT) ? __expf(logit - mx) : 0.0f;
    float sum = e;
    for (int s = 32; s > 0; s >>= 1) sum += __shfl_xor(sum, s, 64);
    if (lane < NT)
        attnP[(size_t)pix * NT + lane] = e / sum;
}

// Weighted 49-tap gather (validated R10/R11): granule-major sX [i][cg4][wp][c4]
// -> conflict-free b128 main loop; XCD-swizzled bh blocks.
__global__ __launch_bounds__(256) void out_kernel4(const float* __restrict__ x,
                                                   const float* __restrict__ attnP,
                                                   float* __restrict__ out)
{
    __shared__ float sX[7 * 4 * HP_ * 4]; // [i][cg4][wp][c4] 30.5 KB
    __shared__ float sA[56 * NT];         // [w][l] 10.7 KB

    int bid = blockIdx.x;                // < 3584
    int g   = bid & 7;                   // presumed XCD
    int s   = bid >> 3;                  // 0..447
    int bh  = g * 28 + (s % 28);         // 28 bh-rows per XCD slot
    int cg  = s / 28;                    // 0..15
    int b   = bh / H_;
    int h   = bh - b * H_;
    int c0  = cg * 16;
    int tid = threadIdx.x;

    for (int idx = tid; idx < 7 * 4 * HP_ * 4; idx += 256)
        sX[idx] = 0.0f;
    __syncthreads();

    {
        const float* ap = attnP + ((size_t)(b * HW_) + h * W_) * NT;
        for (int idx = tid; idx < W_ * NT; idx += 256)
            sA[idx] = ap[idx];
    }
    {
        int c  = tid >> 4;
        int wg = tid & 15;
        const float* xc = x + (size_t)(b * C_ + c0 + c) * HW_;
        int cgr = c >> 2, ce = c & 3;
        #pragma unroll
        for (int i = 0; i < 7; ++i) {
            int ih = h + 2 * i - 6;
            if (ih < 0 || ih >= H_) continue;
            const float* xr = xc + ih * W_;
            #pragma unroll
            for (int k = 0; k < 4; ++k) {
                int w = wg + 16 * k;
                if (w < W_)
                    sX[(((i * 4 + cgr) * HP_) + (w + 6)) * 4 + ce] = xr[w];
            }
        }
    }
    __syncthreads();

    int lane = tid & 63;
    int wid  = tid >> 6;                 // wave -> channels c0+wid*4 .. +3
    int w    = lane;
    bool active = (w < W_);
    int wc = active ? w : (W_ - 1);

    float aR[NT];
    #pragma unroll
    for (int l = 0; l < NT; ++l)
        aR[l] = sA[wc * NT + l];

    f32x4 acc = (f32x4){0.f, 0.f, 0.f, 0.f};
    #pragma unroll
    for (int i = 0; i < 7; ++i) {
        const float* sXi = &sX[(i * 4 + wid) * HP_ * 4];
        #pragma unroll
        for (int j = 0; j < 7; ++j) {
            f32x4 xv = *(const f32x4*)&sXi[(wc + 2 * j) * 4];
            float a = aR[i * 7 + j];
            acc.x += a * xv.x; acc.y += a * xv.y;
            acc.z += a * xv.z; acc.w += a * xv.w;
        }
    }

    if (active) {
        size_t o = ((size_t)(b * C_ + c0 + wid * 4)) * HW_ + h * W_ + w;
        out[o + 0 * HW_] = acc.x;
        out[o + 1 * HW_] = acc.y;
        out[o + 2 * HW_] = acc.z;
        out[o + 3 * HW_] = acc.w;
    }
}

// ===========================================================================
// FALLBACK PATH (R1, proven): used only if ws_size < fast-path need
// ===========================================================================
__global__ __launch_bounds__(256) void wt_kernel(const float* __restrict__ W1,
                                                 float* __restrict__ wT)
{
    int idx = blockIdx.x * 256 + threadIdx.x;
    int oc = idx & 127;
    int ct = idx >> 7;
    wT[idx] = W1[oc * (C_ * NT) + ct];
}

__global__ __launch_bounds__(256) void conv1_kernel(const float* __restrict__ x,
                                                    const float* __restrict__ wT,
                                                    const float* __restrict__ b1,
                                                    float* __restrict__ k)
{
    int tid = threadIdx.x;
    int w   = tid & 63;
    int ty  = tid >> 6;
    int h   = blockIdx.x * 4 + ty;
    int oc0 = blockIdx.y * 8;
    int b   = blockIdx.z;

    const float* xb = x + (size_t)b * C_ * HW_;
    float acc[8] = {0.f,0.f,0.f,0.f,0.f,0.f,0.f,0.f};

    for (int i = 0; i < 7; ++i) {
        int ih = h + 2 * i - 6;
        if (ih < 0 || ih >= H_) continue;
        for (int j = 0; j < 7; ++j) {
            int iw = w + 2 * j - 6;
            bool v  = (iw >= 0) && (iw < W_);
            float m = v ? 1.0f : 0.0f;
            const float* xr = xb + ih * W_ + (v ? iw : 0);
            const float* wr = wT + (size_t)(i * 7 + j) * OC1 + oc0;
            #pragma unroll 4
            for (int c = 0; c < C_; ++c) {
                float xv = m * xr[(size_t)c * HW_];
                const float4 w0 = *(const float4*)(wr + (size_t)c * NT * OC1);
                const float4 w1 = *(const float4*)(wr + (size_t)c * NT * OC1 + 4);
                acc[0] += xv * w0.x; acc[1] += xv * w0.y;
                acc[2] += xv * w0.z; acc[3] += xv * w0.w;
                acc[4] += xv * w1.x; acc[5] += xv * w1.y;
                acc[6] += xv * w1.z; acc[7] += xv * w1.w;
            }
        }
    }
    if (w < W_) {
        size_t o = ((size_t)(b * OC1 + oc0)) * HW_ + h * W_ + w;
        #pragma unroll
        for (int q = 0; q < 8; ++q)
            k[o + (size_t)q * HW_] = acc[q] + b1[oc0 + q];
    }
}

__global__ __launch_bounds__(256) void attn_kernel(const float* __restrict__ kin,
                                                   const float* __restrict__ W2,
                                                   const float* __restrict__ b2,
                                                   float* __restrict__ attn)
{
    __shared__ float sW2[128 * 49];
    int tid = threadIdx.x;
    for (int idx = tid; idx < 128 * 49; idx += 256) {
        int c = idx / 49, l = idx - c * 49;
        sW2[idx] = W2[l * 128 + c];
    }
    __syncthreads();

    int wid  = tid >> 6;
    int lane = tid & 63;
    int pix  = blockIdx.x * 4 + wid;
    int b    = pix / HW_;
    int hw   = pix - b * HW_;
    int l    = (lane < 49) ? lane : 0;

    const float* kb = kin + (size_t)b * OC1 * HW_ + hw;
    float acc = b2[l];
    #pragma unroll 8
    for (int c = 0; c < 128; ++c)
        acc += kb[(size_t)c * HW_] * sW2[c * 49 + l];

    float logit = (lane < 49) ? acc : -INFINITY;
    float mx = logit;
    for (int s = 32; s > 0; s >>= 1) mx = fmaxf(mx, __shfl_xor(mx, s, 64));
    float e = (lane < 49) ? __expf(logit - mx) : 0.0f;
    float sum = e;
    for (int s = 32; s > 0; s >>= 1) sum += __shfl_xor(sum, s, 64);
    if (lane < 49)
        attn[((size_t)b * NT + lane) * HW_ + hw] = e / sum;
}

__global__ __launch_bounds__(256) void out_kernel(const float* __restrict__ x,
                                                  const float* __restrict__ attn,
                                                  float* __restrict__ out)
{
    int idx = blockIdx.x * 256 + threadIdx.x;
    int w  = idx % 56;
    int t  = idx / 56;
    int h  = t % 56;
    int t2 = t / 56;
    int c  = t2 & 255;
    int b  = t2 >> 8;

    const float* xb = x + (size_t)(b * C_ + c) * HW_;
    const float* ab = attn + (size_t)b * NT * HW_ + h * W_ + w;

    float acc = 0.f;
    #pragma unroll
    for (int i = 0; i < 7; ++i) {
        int ih = h + 2 * i - 6;
        bool hv = (ih >= 0) && (ih < H_);
        #pragma unroll
        for (int j = 0; j < 7; ++j) {
            int iw = w + 2 * j - 6;
            bool v  = hv && (iw >= 0) && (iw < W_);
            float m = v ? 1.0f : 0.0f;
            int off = v ? (ih * W_ + iw) : 0;
            acc += (m * xb[off]) * ab[(size_t)(i * 7 + j) * HW_];
        }
    }
    out[idx] = acc;
}

// ===========================================================================
extern "C" void kernel_launch(void* const* d_in, const int* in_sizes, int n_in,
                              void* d_out, int out_size, void* d_ws, size_t ws_size,
                              hipStream_t stream)
{
    const float* x  = (const float*)d_in[0];
    const float* W1 = (const float*)d_in[1];
    const float* b1 = (const float*)d_in[2];
    const float* W2 = (const float*)d_in[3];
    const float* b2 = (const float*)d_in[4];
    float* out = (float*)d_out;

    // fast-path ws layout (bytes)
    const size_t xp_b    = (size_t)B_ * HP_ * HP_ * 256 * 2;        //  9,469,952
    const size_t wfb_b   = (size_t)NT * 8 * 4 * 64 * 8 * 2;         //  1,605,632
    const size_t kpart_b = (size_t)NSL * M_TOT * NP * 2;            // 22,478,848 (bf16)
    const size_t attn_b  = (size_t)M_TOT * NT * 4;                  //  2,458,624
    const size_t cb_b    = 256;
    const size_t need = xp_b + wfb_b + kpart_b + attn_b + cb_b;     // ~36.0 MB

    if (ws_size >= need) {
        char* base = (char*)d_ws;
        __hip_bfloat16* xp    = (__hip_bfloat16*)base;
        __hip_bfloat16* wfb   = (__hip_bfloat16*)(base + xp_b);
        __hip_bfloat16* kpart = (__hip_bfloat16*)(base + xp_b + wfb_b);
        float* attnP = (float*)(base + xp_b + wfb_b + kpart_b);
        float* cb    = (float*)(base + xp_b + wfb_b + kpart_b + attn_b);

        xpack2_kernel<<<2176, 256, 0, stream>>>(x, xp);
        wfuse_kernel <<<dim3(49, 8), 256, 0, stream>>>(W1, W2, b1, b2, wfb, cb);
        conv1_mfma7  <<<784, 256, 0, stream>>>(xp, wfb, kpart);
        attn_fold2   <<<3136, 256, 0, stream>>>((const unsigned short*)kpart, cb, attnP);
        out_kernel4  <<<3584, 256, 0, stream>>>(x, attnP, out);
    } else {
        // R1 fallback (~14.6 MB)
        float* wT   = (float*)d_ws;
        float* kbuf = wT + 1605632;
        float* attn = kbuf + 1605632;
        wt_kernel   <<<6272, 256, 0, stream>>>(W1, wT);
        conv1_kernel<<<dim3(14, 16, 4), 256, 0, stream>>>(x, wT, b1, kbuf);
        attn_kernel <<<3136, 256, 0, stream>>>(kbuf, W2, b2, attn);
        out_kernel  <<<12544, 256, 0, stream>>>(x, attn, out);
    }
}